// Round 1
// baseline (813.803 us; speedup 1.0000x reference)
//
#include <hip/hip_runtime.h>

#define N_NODES 50000
#define N_EDGES 600000
#define N_GRAPHS 64
#define N_LAYERS 4
#define D 128
#define BN_EPS 1e-5f

#define SCAN_NB 49  // ceil(50000/1024)

// ---------------- embedding gather ----------------
__global__ __launch_bounds__(256) void embed_kernel(const int* __restrict__ idx,
    const float* __restrict__ emb, float* __restrict__ x) {
  int tid = blockIdx.x * 256 + threadIdx.x;
  if (tid >= N_NODES * 32) return;
  int n = tid >> 5, c4 = tid & 31;
  int e = idx[n];
  ((float4*)x)[(size_t)n * 32 + c4] = ((const float4*)emb)[(size_t)e * 32 + c4];
}

// ---------------- CSR build ----------------
__global__ __launch_bounds__(256) void count_kernel(const int* __restrict__ dst,
    int* __restrict__ counts) {
  int e = blockIdx.x * 256 + threadIdx.x;
  if (e < N_EDGES) atomicAdd(&counts[dst[e]], 1);
}

__global__ __launch_bounds__(256) void scan_block_kernel(const int* __restrict__ counts,
    int* __restrict__ offsets, int* __restrict__ partials) {
  __shared__ int s[256];
  int t = threadIdx.x;
  int base = blockIdx.x * 1024 + t * 4;
  int v[4];
#pragma unroll
  for (int i = 0; i < 4; ++i) v[i] = (base + i < N_NODES) ? counts[base + i] : 0;
  int tsum = v[0] + v[1] + v[2] + v[3];
  s[t] = tsum;
  __syncthreads();
  for (int off = 1; off < 256; off <<= 1) {
    int add = (t >= off) ? s[t - off] : 0;
    __syncthreads();
    s[t] += add;
    __syncthreads();
  }
  int run = s[t] - tsum;  // exclusive within block
#pragma unroll
  for (int i = 0; i < 4; ++i) {
    if (base + i < N_NODES) offsets[base + i] = run;
    run += v[i];
  }
  if (t == 255) partials[blockIdx.x] = s[255];
}

__global__ void scan_partials_kernel(int* partials) {
  if (threadIdx.x == 0) {
    int run = 0;
    for (int b = 0; b < SCAN_NB; ++b) { int v = partials[b]; partials[b] = run; run += v; }
  }
}

__global__ __launch_bounds__(256) void add_offsets_kernel(int* __restrict__ offsets,
    const int* __restrict__ partials, int* __restrict__ cursor) {
  int i = blockIdx.x * 256 + threadIdx.x;
  if (i < N_NODES) {
    int o = offsets[i] + partials[i >> 10];
    offsets[i] = o;
    cursor[i] = o;
  }
  if (blockIdx.x == 0 && threadIdx.x == 0) offsets[N_NODES] = N_EDGES;
}

__global__ __launch_bounds__(256) void fill_csr_kernel(const int* __restrict__ src,
    const int* __restrict__ dst, int* __restrict__ cursor, int* __restrict__ col) {
  int e = blockIdx.x * 256 + threadIdx.x;
  if (e < N_EDGES) {
    int d = dst[e];
    int p = atomicAdd(&cursor[d], 1);
    col[p] = src[e];
  }
}

// ---------------- aggregation: h = x + sum_{src->node} x[src] ----------------
__global__ __launch_bounds__(256) void agg_kernel(const float* __restrict__ x,
    const int* __restrict__ offsets, const int* __restrict__ col, float* __restrict__ h) {
  int node = blockIdx.x * 4 + (threadIdx.x >> 6);
  if (node >= N_NODES) return;
  int lane = threadIdx.x & 63;
  const float2* x2 = (const float2*)x;
  float2 acc = x2[(size_t)node * 64 + lane];
  int beg = offsets[node], end = offsets[node + 1];
  for (int e = beg; e < end; ++e) {
    int s = col[e];
    float2 v = x2[(size_t)s * 64 + lane];
    acc.x += v.x;
    acc.y += v.y;
  }
  ((float2*)h)[(size_t)node * 64 + lane] = acc;
}

// ---------------- GEMM (+optional fused bn-relu on input) + column stats ----------------
template <bool TRANS>
__global__ __launch_bounds__(256) void gemm_bn_kernel(
    const float* __restrict__ A, const float* __restrict__ W, const float* __restrict__ bias,
    const float* __restrict__ scale, const float* __restrict__ shift,
    float* __restrict__ Y, float* __restrict__ ssum, float* __restrict__ ssq) {
  __shared__ float a_lds[64][132];
  __shared__ float w_lds[64][132];
  int t = threadIdx.x;
  int row0 = blockIdx.x * 64;
  int tx = t & 15, ty = t >> 4;
  int tx8 = tx * 8, ty4 = ty * 4;
  float acc[4][8];
#pragma unroll
  for (int i = 0; i < 4; ++i)
#pragma unroll
    for (int j = 0; j < 8; ++j) acc[i][j] = 0.f;

  // stage A tile (64 rows x 128 k), with optional bn-relu transform
#pragma unroll
  for (int i = 0; i < 8; ++i) {
    int s = t + i * 256;
    int r = s >> 5, c4 = s & 31;
    int row = row0 + r;
    float4 v = make_float4(0.f, 0.f, 0.f, 0.f);
    if (row < N_NODES) v = ((const float4*)A)[(size_t)row * 32 + c4];
    if (TRANS) {
      float4 sc = ((const float4*)scale)[c4];
      float4 sh = ((const float4*)shift)[c4];
      v.x = fmaxf(fmaf(v.x, sc.x, sh.x), 0.f);
      v.y = fmaxf(fmaf(v.y, sc.y, sh.y), 0.f);
      v.z = fmaxf(fmaf(v.z, sc.z, sh.z), 0.f);
      v.w = fmaxf(fmaf(v.w, sc.w, sh.w), 0.f);
    }
    *(float4*)&a_lds[r][c4 * 4] = v;
  }

  for (int kk = 0; kk < 128; kk += 64) {
    __syncthreads();
    // stage W chunk (64 k x 128 cols)
#pragma unroll
    for (int i = 0; i < 8; ++i) {
      int s = t + i * 256;
      int r = s >> 5, c4 = s & 31;
      float4 v = ((const float4*)W)[(size_t)(kk + r) * 32 + c4];
      *(float4*)&w_lds[r][c4 * 4] = v;
    }
    __syncthreads();
#pragma unroll 8
    for (int k = 0; k < 64; ++k) {
      float a[4];
      a[0] = a_lds[ty4 + 0][kk + k];
      a[1] = a_lds[ty4 + 1][kk + k];
      a[2] = a_lds[ty4 + 2][kk + k];
      a[3] = a_lds[ty4 + 3][kk + k];
      float4 w0 = *(const float4*)&w_lds[k][tx8];
      float4 w1 = *(const float4*)&w_lds[k][tx8 + 4];
#pragma unroll
      for (int i = 0; i < 4; ++i) {
        acc[i][0] = fmaf(a[i], w0.x, acc[i][0]);
        acc[i][1] = fmaf(a[i], w0.y, acc[i][1]);
        acc[i][2] = fmaf(a[i], w0.z, acc[i][2]);
        acc[i][3] = fmaf(a[i], w0.w, acc[i][3]);
        acc[i][4] = fmaf(a[i], w1.x, acc[i][4]);
        acc[i][5] = fmaf(a[i], w1.y, acc[i][5]);
        acc[i][6] = fmaf(a[i], w1.z, acc[i][6]);
        acc[i][7] = fmaf(a[i], w1.w, acc[i][7]);
      }
    }
  }

  // epilogue: add bias, write Y, accumulate per-column sum / sumsq
  float b[8];
  *(float4*)&b[0] = ((const float4*)bias)[tx * 2];
  *(float4*)&b[4] = ((const float4*)bias)[tx * 2 + 1];
  float csum[8], csq[8];
#pragma unroll
  for (int j = 0; j < 8; ++j) { csum[j] = 0.f; csq[j] = 0.f; }
#pragma unroll
  for (int i = 0; i < 4; ++i) {
    int row = row0 + ty4 + i;
    if (row < N_NODES) {
      float yv[8];
#pragma unroll
      for (int j = 0; j < 8; ++j) {
        yv[j] = acc[i][j] + b[j];
        csum[j] += yv[j];
        csq[j] += yv[j] * yv[j];
      }
      ((float4*)Y)[(size_t)row * 32 + tx * 2] = *(float4*)&yv[0];
      ((float4*)Y)[(size_t)row * 32 + tx * 2 + 1] = *(float4*)&yv[4];
    }
  }
  __syncthreads();  // done reading a_lds; reuse as reduction scratch
  float* red = &a_lds[0][0];
#pragma unroll
  for (int j = 0; j < 8; ++j) red[ty * 128 + tx8 + j] = csum[j];
  __syncthreads();
  if (t < 128) {
    float s = 0.f;
#pragma unroll
    for (int i = 0; i < 16; ++i) s += red[i * 128 + t];
    atomicAdd(&ssum[t], s);
  }
  __syncthreads();
#pragma unroll
  for (int j = 0; j < 8; ++j) red[ty * 128 + tx8 + j] = csq[j];
  __syncthreads();
  if (t < 128) {
    float s = 0.f;
#pragma unroll
    for (int i = 0; i < 16; ++i) s += red[i * 128 + t];
    atomicAdd(&ssq[t], s);
  }
}

// ---------------- BN finalize: scale/shift per column ----------------
__global__ void finalize_kernel(const float* __restrict__ ssum, const float* __restrict__ ssq,
    const float* __restrict__ g, const float* __restrict__ b,
    float* __restrict__ scale, float* __restrict__ shift) {
  int c = threadIdx.x;
  float mu = ssum[c] * (1.0f / N_NODES);
  float var = fmaxf(ssq[c] * (1.0f / N_NODES) - mu * mu, 0.f);
  float s = g[c] * rsqrtf(var + BN_EPS);
  scale[c] = s;
  shift[c] = fmaf(-mu, s, b[c]);
}

// ---------------- elementwise bn + relu ----------------
__global__ __launch_bounds__(256) void bnrelu_kernel(const float* __restrict__ z,
    const float* __restrict__ scale, const float* __restrict__ shift, float* __restrict__ x) {
  int tid = blockIdx.x * 256 + threadIdx.x;
  if (tid >= N_NODES * 32) return;
  int c4 = tid & 31;
  float4 v = ((const float4*)z)[tid];
  float4 sc = ((const float4*)scale)[c4];
  float4 sh = ((const float4*)shift)[c4];
  v.x = fmaxf(fmaf(v.x, sc.x, sh.x), 0.f);
  v.y = fmaxf(fmaf(v.y, sc.y, sh.y), 0.f);
  v.z = fmaxf(fmaf(v.z, sc.z, sh.z), 0.f);
  v.w = fmaxf(fmaf(v.w, sc.w, sh.w), 0.f);
  ((float4*)x)[tid] = v;
}

// ---------------- pooling (batch is sorted) ----------------
__device__ __forceinline__ int lower_bound_batch(const int* __restrict__ batch, int key) {
  int lo = 0, hi = N_NODES;
  while (lo < hi) {
    int mid = (lo + hi) >> 1;
    if (batch[mid] < key) lo = mid + 1; else hi = mid;
  }
  return lo;
}

__global__ __launch_bounds__(256) void pool_kernel(const float* __restrict__ x,
    const int* __restrict__ batch, float* __restrict__ pooled, float* __restrict__ gcnt) {
  int g = blockIdx.x, chunk = blockIdx.y;
  int lo = lower_bound_batch(batch, g);
  int hi = lower_bound_batch(batch, g + 1);
  int f = threadIdx.x & 127, sub = threadIdx.x >> 7;
  int cnt = hi - lo;
  int per = (cnt + 7) >> 3;
  int s = lo + chunk * per;
  int e = min(s + per, hi);
  float acc = 0.f;
  for (int n = s + sub; n < e; n += 2) acc += x[(size_t)n * 128 + f];
  __shared__ float red[2][128];
  red[sub][f] = acc;
  __syncthreads();
  if (sub == 0) atomicAdd(&pooled[g * 128 + f], red[0][f] + red[1][f]);
  if (threadIdx.x == 0 && chunk == 0) gcnt[g] = (float)cnt;
}

// ---------------- final MLP: relu(pooled/cnt @ W1 + b1) @ W2 + b2 ----------------
__global__ __launch_bounds__(256) void mlp_kernel(const float* __restrict__ pooled,
    const float* __restrict__ gcnt, const float* __restrict__ w1, const float* __restrict__ b1,
    const float* __restrict__ w2, const float* __restrict__ b2, float* __restrict__ out) {
  int g = blockIdx.x, t = threadIdx.x;
  __shared__ float p[128];
  __shared__ float hbuf[256];
  if (t < 128) p[t] = pooled[g * 128 + t] / fmaxf(gcnt[g], 1.0f);
  __syncthreads();
  float acc = b1[t];
  for (int k = 0; k < 128; ++k) acc = fmaf(p[k], w1[k * 256 + t], acc);
  hbuf[t] = fmaxf(acc, 0.f);
  __syncthreads();
  if (t < 10) {
    float o = b2[t];
    for (int k = 0; k < 256; ++k) o = fmaf(hbuf[k], w2[k * 10 + t], o);
    out[g * 10 + t] = o;
  }
}

// ---------------- launch ----------------
extern "C" void kernel_launch(void* const* d_in, const int* in_sizes, int n_in,
                              void* d_out, int out_size, void* d_ws, size_t ws_size,
                              hipStream_t stream) {
  const int* x_node = (const int*)d_in[0];
  const int* eidx = (const int*)d_in[1];
  const int* batch = (const int*)d_in[2];
  const float* emb = (const float*)d_in[3];
  const float* cw1 = (const float*)d_in[4];
  const float* cb1 = (const float*)d_in[5];
  const float* bn1g = (const float*)d_in[6];
  const float* bn1b = (const float*)d_in[7];
  const float* cw2 = (const float*)d_in[8];
  const float* cb2 = (const float*)d_in[9];
  const float* bn2g = (const float*)d_in[10];
  const float* bn2b = (const float*)d_in[11];
  const float* l1w = (const float*)d_in[12];
  const float* l1b = (const float*)d_in[13];
  const float* l2w = (const float*)d_in[14];
  const float* l2b = (const float*)d_in[15];
  float* out = (float*)d_out;

  char* ws = (char*)d_ws;
  size_t off = 0;
  auto carve = [&](size_t bytes) -> void* {
    void* p = ws + off;
    off += (bytes + 255) & ~(size_t)255;
    return p;
  };
  float* xbuf = (float*)carve((size_t)N_NODES * D * 4);
  float* hbuf = (float*)carve((size_t)N_NODES * D * 4);
  float* ybuf = (float*)carve((size_t)N_NODES * D * 4);
  int* counts = (int*)carve((size_t)N_NODES * 4);
  int* offsets = (int*)carve((size_t)(N_NODES + 1) * 4);
  int* cursor = (int*)carve((size_t)N_NODES * 4);
  int* col = (int*)carve((size_t)N_EDGES * 4);
  int* partials = (int*)carve(64 * 4);
  float* ssum = (float*)carve(8 * 128 * 4);
  float* ssq = (float*)carve(8 * 128 * 4);
  float* scaleb = (float*)carve(8 * 128 * 4);
  float* shiftb = (float*)carve(8 * 128 * 4);
  float* pooled = (float*)carve(64 * 128 * 4);
  float* gcnt = (float*)carve(64 * 4);
  (void)ws_size;
  (void)in_sizes;
  (void)n_in;
  (void)out_size;

  const int* srcp = eidx;
  const int* dstp = eidx + N_EDGES;

  hipMemsetAsync(counts, 0, (size_t)N_NODES * 4, stream);
  hipMemsetAsync(ssum, 0, 8 * 128 * 4, stream);
  hipMemsetAsync(ssq, 0, 8 * 128 * 4, stream);
  hipMemsetAsync(pooled, 0, 64 * 128 * 4, stream);
  hipMemsetAsync(gcnt, 0, 64 * 4, stream);

  embed_kernel<<<6250, 256, 0, stream>>>(x_node, emb, xbuf);
  count_kernel<<<(N_EDGES + 255) / 256, 256, 0, stream>>>(dstp, counts);
  scan_block_kernel<<<SCAN_NB, 256, 0, stream>>>(counts, offsets, partials);
  scan_partials_kernel<<<1, 64, 0, stream>>>(partials);
  add_offsets_kernel<<<(N_NODES + 255) / 256, 256, 0, stream>>>(offsets, partials, cursor);
  fill_csr_kernel<<<(N_EDGES + 255) / 256, 256, 0, stream>>>(srcp, dstp, cursor, col);

  for (int l = 0; l < N_LAYERS; ++l) {
    const float* W1 = cw1 + (size_t)l * D * D;
    const float* W2 = cw2 + (size_t)l * D * D;
    float* s1s = ssum + (l * 2) * 128;
    float* s1q = ssq + (l * 2) * 128;
    float* s2s = ssum + (l * 2 + 1) * 128;
    float* s2q = ssq + (l * 2 + 1) * 128;
    float* sc1 = scaleb + (l * 2) * 128;
    float* sh1 = shiftb + (l * 2) * 128;
    float* sc2 = scaleb + (l * 2 + 1) * 128;
    float* sh2 = shiftb + (l * 2 + 1) * 128;

    agg_kernel<<<12500, 256, 0, stream>>>(xbuf, offsets, col, hbuf);
    gemm_bn_kernel<false><<<782, 256, 0, stream>>>(hbuf, W1, cb1 + l * D, nullptr, nullptr,
                                                   ybuf, s1s, s1q);
    finalize_kernel<<<1, 128, 0, stream>>>(s1s, s1q, bn1g + l * D, bn1b + l * D, sc1, sh1);
    gemm_bn_kernel<true><<<782, 256, 0, stream>>>(ybuf, W2, cb2 + l * D, sc1, sh1,
                                                  hbuf, s2s, s2q);
    finalize_kernel<<<1, 128, 0, stream>>>(s2s, s2q, bn2g + l * D, bn2b + l * D, sc2, sh2);
    bnrelu_kernel<<<6250, 256, 0, stream>>>(hbuf, sc2, sh2, xbuf);
  }

  pool_kernel<<<dim3(64, 8), 256, 0, stream>>>(xbuf, batch, pooled, gcnt);
  mlp_kernel<<<64, 256, 0, stream>>>(pooled, gcnt, l1w, l1b, l2w, l2b, out);
}

// Round 2
// 693.750 us; speedup vs baseline: 1.1730x; 1.1730x over previous
//
#include <hip/hip_runtime.h>

#define N_NODES 50000
#define N_EDGES 600000
#define N_GRAPHS 64
#define N_LAYERS 4
#define D 128
#define BN_EPS 1e-5f

#define SCAN_NB 49  // ceil(50000/1024)

// ---------------- embedding gather ----------------
__global__ __launch_bounds__(256) void embed_kernel(const int* __restrict__ idx,
    const float* __restrict__ emb, float* __restrict__ x) {
  int tid = blockIdx.x * 256 + threadIdx.x;
  if (tid >= N_NODES * 32) return;
  int n = tid >> 5, c4 = tid & 31;
  int e = idx[n];
  ((float4*)x)[(size_t)n * 32 + c4] = ((const float4*)emb)[(size_t)e * 32 + c4];
}

// ---------------- CSR build ----------------
__global__ __launch_bounds__(256) void count_kernel(const int* __restrict__ dst,
    int* __restrict__ counts) {
  int e = blockIdx.x * 256 + threadIdx.x;
  if (e < N_EDGES) atomicAdd(&counts[dst[e]], 1);
}

__global__ __launch_bounds__(256) void scan_block_kernel(const int* __restrict__ counts,
    int* __restrict__ offsets, int* __restrict__ partials) {
  __shared__ int s[256];
  int t = threadIdx.x;
  int base = blockIdx.x * 1024 + t * 4;
  int v[4];
#pragma unroll
  for (int i = 0; i < 4; ++i) v[i] = (base + i < N_NODES) ? counts[base + i] : 0;
  int tsum = v[0] + v[1] + v[2] + v[3];
  s[t] = tsum;
  __syncthreads();
  for (int off = 1; off < 256; off <<= 1) {
    int add = (t >= off) ? s[t - off] : 0;
    __syncthreads();
    s[t] += add;
    __syncthreads();
  }
  int run = s[t] - tsum;  // exclusive within block
#pragma unroll
  for (int i = 0; i < 4; ++i) {
    if (base + i < N_NODES) offsets[base + i] = run;
    run += v[i];
  }
  if (t == 255) partials[blockIdx.x] = s[255];
}

__global__ void scan_partials_kernel(int* partials) {
  if (threadIdx.x == 0) {
    int run = 0;
    for (int b = 0; b < SCAN_NB; ++b) { int v = partials[b]; partials[b] = run; run += v; }
  }
}

__global__ __launch_bounds__(256) void add_offsets_kernel(int* __restrict__ offsets,
    const int* __restrict__ partials, int* __restrict__ cursor) {
  int i = blockIdx.x * 256 + threadIdx.x;
  if (i < N_NODES) {
    int o = offsets[i] + partials[i >> 10];
    offsets[i] = o;
    cursor[i] = o;
  }
  if (blockIdx.x == 0 && threadIdx.x == 0) offsets[N_NODES] = N_EDGES;
}

__global__ __launch_bounds__(256) void fill_csr_kernel(const int* __restrict__ src,
    const int* __restrict__ dst, int* __restrict__ cursor, int* __restrict__ col) {
  int e = blockIdx.x * 256 + threadIdx.x;
  if (e < N_EDGES) {
    int d = dst[e];
    int p = atomicAdd(&cursor[d], 1);
    col[p] = src[e];
  }
}

// ---- aggregation: h = t(x[node]) + sum_{src->node} t(x[src]),
//      t = optional fused bn-relu of the PREVIOUS layer ----
template <bool TRANS>
__global__ __launch_bounds__(256) void agg_kernel(const float* __restrict__ x,
    const int* __restrict__ offsets, const int* __restrict__ col,
    const float* __restrict__ scale, const float* __restrict__ shift,
    float* __restrict__ h) {
  int node = blockIdx.x * 4 + (threadIdx.x >> 6);
  int lane = threadIdx.x & 63;
  float2 sc, sh;
  if (TRANS) {
    sc = ((const float2*)scale)[lane];
    sh = ((const float2*)shift)[lane];
  }
  const float2* x2 = (const float2*)x;
  float2 self = x2[(size_t)node * 64 + lane];
  float2 acc;
  if (TRANS) {
    acc.x = fmaxf(fmaf(self.x, sc.x, sh.x), 0.f);
    acc.y = fmaxf(fmaf(self.y, sc.y, sh.y), 0.f);
  } else {
    acc = self;
  }
  int beg = offsets[node], end = offsets[node + 1];
  for (int e = beg; e < end; e += 4) {
    // 4 predicated gathers in flight (clamped index keeps loads valid)
    int   idx[4];
    bool  val[4];
#pragma unroll
    for (int i = 0; i < 4; ++i) {
      val[i] = (e + i) < end;
      idx[i] = val[i] ? (e + i) : e;
    }
    int s0 = col[idx[0]], s1 = col[idx[1]], s2 = col[idx[2]], s3 = col[idx[3]];
    float2 v0 = x2[(size_t)s0 * 64 + lane];
    float2 v1 = x2[(size_t)s1 * 64 + lane];
    float2 v2 = x2[(size_t)s2 * 64 + lane];
    float2 v3 = x2[(size_t)s3 * 64 + lane];
    float2 vv[4] = {v0, v1, v2, v3};
#pragma unroll
    for (int i = 0; i < 4; ++i) {
      float2 v = vv[i];
      if (TRANS) {
        v.x = fmaxf(fmaf(v.x, sc.x, sh.x), 0.f);
        v.y = fmaxf(fmaf(v.y, sc.y, sh.y), 0.f);
      }
      if (val[i]) {
        acc.x += v.x;
        acc.y += v.y;
      }
    }
  }
  ((float2*)h)[(size_t)node * 64 + lane] = acc;
}

// ---------------- GEMM (+optional fused bn-relu on input) + column stats ----------------
template <bool TRANS>
__global__ __launch_bounds__(256) void gemm_bn_kernel(
    const float* __restrict__ A, const float* __restrict__ W, const float* __restrict__ bias,
    const float* __restrict__ scale, const float* __restrict__ shift,
    float* __restrict__ Y, float* __restrict__ ssum, float* __restrict__ ssq) {
  __shared__ float a_lds[64][132];
  __shared__ float w_lds[64][132];
  int t = threadIdx.x;
  int row0 = blockIdx.x * 64;
  int tx = t & 15, ty = t >> 4;
  int tx8 = tx * 8, ty4 = ty * 4;
  float acc[4][8];
#pragma unroll
  for (int i = 0; i < 4; ++i)
#pragma unroll
    for (int j = 0; j < 8; ++j) acc[i][j] = 0.f;

  // stage A tile (64 rows x 128 k), with optional bn-relu transform
#pragma unroll
  for (int i = 0; i < 8; ++i) {
    int s = t + i * 256;
    int r = s >> 5, c4 = s & 31;
    int row = row0 + r;
    float4 v = make_float4(0.f, 0.f, 0.f, 0.f);
    if (row < N_NODES) v = ((const float4*)A)[(size_t)row * 32 + c4];
    if (TRANS) {
      float4 sc = ((const float4*)scale)[c4];
      float4 sh = ((const float4*)shift)[c4];
      v.x = fmaxf(fmaf(v.x, sc.x, sh.x), 0.f);
      v.y = fmaxf(fmaf(v.y, sc.y, sh.y), 0.f);
      v.z = fmaxf(fmaf(v.z, sc.z, sh.z), 0.f);
      v.w = fmaxf(fmaf(v.w, sc.w, sh.w), 0.f);
    }
    *(float4*)&a_lds[r][c4 * 4] = v;
  }

  for (int kk = 0; kk < 128; kk += 64) {
    __syncthreads();
    // stage W chunk (64 k x 128 cols)
#pragma unroll
    for (int i = 0; i < 8; ++i) {
      int s = t + i * 256;
      int r = s >> 5, c4 = s & 31;
      float4 v = ((const float4*)W)[(size_t)(kk + r) * 32 + c4];
      *(float4*)&w_lds[r][c4 * 4] = v;
    }
    __syncthreads();
#pragma unroll 8
    for (int k = 0; k < 64; ++k) {
      float a[4];
      a[0] = a_lds[ty4 + 0][kk + k];
      a[1] = a_lds[ty4 + 1][kk + k];
      a[2] = a_lds[ty4 + 2][kk + k];
      a[3] = a_lds[ty4 + 3][kk + k];
      float4 w0 = *(const float4*)&w_lds[k][tx8];
      float4 w1 = *(const float4*)&w_lds[k][tx8 + 4];
#pragma unroll
      for (int i = 0; i < 4; ++i) {
        acc[i][0] = fmaf(a[i], w0.x, acc[i][0]);
        acc[i][1] = fmaf(a[i], w0.y, acc[i][1]);
        acc[i][2] = fmaf(a[i], w0.z, acc[i][2]);
        acc[i][3] = fmaf(a[i], w0.w, acc[i][3]);
        acc[i][4] = fmaf(a[i], w1.x, acc[i][4]);
        acc[i][5] = fmaf(a[i], w1.y, acc[i][5]);
        acc[i][6] = fmaf(a[i], w1.z, acc[i][6]);
        acc[i][7] = fmaf(a[i], w1.w, acc[i][7]);
      }
    }
  }

  // epilogue: add bias, write Y, accumulate per-column sum / sumsq
  float b[8];
  *(float4*)&b[0] = ((const float4*)bias)[tx * 2];
  *(float4*)&b[4] = ((const float4*)bias)[tx * 2 + 1];
  float csum[8], csq[8];
#pragma unroll
  for (int j = 0; j < 8; ++j) { csum[j] = 0.f; csq[j] = 0.f; }
#pragma unroll
  for (int i = 0; i < 4; ++i) {
    int row = row0 + ty4 + i;
    if (row < N_NODES) {
      float yv[8];
#pragma unroll
      for (int j = 0; j < 8; ++j) {
        yv[j] = acc[i][j] + b[j];
        csum[j] += yv[j];
        csq[j] += yv[j] * yv[j];
      }
      ((float4*)Y)[(size_t)row * 32 + tx * 2] = *(float4*)&yv[0];
      ((float4*)Y)[(size_t)row * 32 + tx * 2 + 1] = *(float4*)&yv[4];
    }
  }
  __syncthreads();  // done reading a_lds; reuse as reduction scratch
  float* red = &a_lds[0][0];
#pragma unroll
  for (int j = 0; j < 8; ++j) red[ty * 128 + tx8 + j] = csum[j];
  __syncthreads();
  if (t < 128) {
    float s = 0.f;
#pragma unroll
    for (int i = 0; i < 16; ++i) s += red[i * 128 + t];
    atomicAdd(&ssum[t], s);
  }
  __syncthreads();
#pragma unroll
  for (int j = 0; j < 8; ++j) red[ty * 128 + tx8 + j] = csq[j];
  __syncthreads();
  if (t < 128) {
    float s = 0.f;
#pragma unroll
    for (int i = 0; i < 16; ++i) s += red[i * 128 + t];
    atomicAdd(&ssq[t], s);
  }
}

// ---------------- BN finalize: scale/shift per column ----------------
__global__ void finalize_kernel(const float* __restrict__ ssum, const float* __restrict__ ssq,
    const float* __restrict__ g, const float* __restrict__ b,
    float* __restrict__ scale, float* __restrict__ shift) {
  int c = threadIdx.x;
  float mu = ssum[c] * (1.0f / N_NODES);
  float var = fmaxf(ssq[c] * (1.0f / N_NODES) - mu * mu, 0.f);
  float s = g[c] * rsqrtf(var + BN_EPS);
  scale[c] = s;
  shift[c] = fmaf(-mu, s, b[c]);
}

// ---------------- pooling (batch is sorted); applies final bn-relu ----------------
__device__ __forceinline__ int lower_bound_batch(const int* __restrict__ batch, int key) {
  int lo = 0, hi = N_NODES;
  while (lo < hi) {
    int mid = (lo + hi) >> 1;
    if (batch[mid] < key) lo = mid + 1; else hi = mid;
  }
  return lo;
}

__global__ __launch_bounds__(256) void pool_kernel(const float* __restrict__ x,
    const int* __restrict__ batch, const float* __restrict__ scale,
    const float* __restrict__ shift, float* __restrict__ pooled, float* __restrict__ gcnt) {
  int g = blockIdx.x, chunk = blockIdx.y;
  int lo = lower_bound_batch(batch, g);
  int hi = lower_bound_batch(batch, g + 1);
  int f = threadIdx.x & 127, sub = threadIdx.x >> 7;
  float sc = scale[f], sh = shift[f];
  int cnt = hi - lo;
  int per = (cnt + 7) >> 3;
  int s = lo + chunk * per;
  int e = min(s + per, hi);
  float acc = 0.f;
  for (int n = s + sub; n < e; n += 2)
    acc += fmaxf(fmaf(x[(size_t)n * 128 + f], sc, sh), 0.f);
  __shared__ float red[2][128];
  red[sub][f] = acc;
  __syncthreads();
  if (sub == 0) atomicAdd(&pooled[g * 128 + f], red[0][f] + red[1][f]);
  if (threadIdx.x == 0 && chunk == 0) gcnt[g] = (float)cnt;
}

// ---------------- final MLP: relu(pooled/cnt @ W1 + b1) @ W2 + b2 ----------------
__global__ __launch_bounds__(256) void mlp_kernel(const float* __restrict__ pooled,
    const float* __restrict__ gcnt, const float* __restrict__ w1, const float* __restrict__ b1,
    const float* __restrict__ w2, const float* __restrict__ b2, float* __restrict__ out) {
  int g = blockIdx.x, t = threadIdx.x;
  __shared__ float p[128];
  __shared__ float hbuf[256];
  if (t < 128) p[t] = pooled[g * 128 + t] / fmaxf(gcnt[g], 1.0f);
  __syncthreads();
  float acc = b1[t];
  for (int k = 0; k < 128; ++k) acc = fmaf(p[k], w1[k * 256 + t], acc);
  hbuf[t] = fmaxf(acc, 0.f);
  __syncthreads();
  if (t < 10) {
    float o = b2[t];
    for (int k = 0; k < 256; ++k) o = fmaf(hbuf[k], w2[k * 10 + t], o);
    out[g * 10 + t] = o;
  }
}

// ---------------- launch ----------------
extern "C" void kernel_launch(void* const* d_in, const int* in_sizes, int n_in,
                              void* d_out, int out_size, void* d_ws, size_t ws_size,
                              hipStream_t stream) {
  const int* x_node = (const int*)d_in[0];
  const int* eidx = (const int*)d_in[1];
  const int* batch = (const int*)d_in[2];
  const float* emb = (const float*)d_in[3];
  const float* cw1 = (const float*)d_in[4];
  const float* cb1 = (const float*)d_in[5];
  const float* bn1g = (const float*)d_in[6];
  const float* bn1b = (const float*)d_in[7];
  const float* cw2 = (const float*)d_in[8];
  const float* cb2 = (const float*)d_in[9];
  const float* bn2g = (const float*)d_in[10];
  const float* bn2b = (const float*)d_in[11];
  const float* l1w = (const float*)d_in[12];
  const float* l1b = (const float*)d_in[13];
  const float* l2w = (const float*)d_in[14];
  const float* l2b = (const float*)d_in[15];
  float* out = (float*)d_out;

  char* ws = (char*)d_ws;
  size_t off = 0;
  auto carve = [&](size_t bytes) -> void* {
    void* p = ws + off;
    off += (bytes + 255) & ~(size_t)255;
    return p;
  };
  float* hbuf = (float*)carve((size_t)N_NODES * D * 4);  // layer input (raw z, pre-bn)
  float* abuf = (float*)carve((size_t)N_NODES * D * 4);  // agg output
  float* ybuf = (float*)carve((size_t)N_NODES * D * 4);  // gemm1 output (raw z1)
  int* counts = (int*)carve((size_t)N_NODES * 4);
  int* offsets = (int*)carve((size_t)(N_NODES + 1) * 4);
  int* cursor = (int*)carve((size_t)N_NODES * 4);
  int* col = (int*)carve((size_t)N_EDGES * 4);
  int* partials = (int*)carve(64 * 4);
  float* ssum = (float*)carve(8 * 128 * 4);
  float* ssq = (float*)carve(8 * 128 * 4);
  float* scaleb = (float*)carve(8 * 128 * 4);
  float* shiftb = (float*)carve(8 * 128 * 4);
  float* pooled = (float*)carve(64 * 128 * 4);
  float* gcnt = (float*)carve(64 * 4);
  (void)ws_size;
  (void)in_sizes;
  (void)n_in;
  (void)out_size;

  const int* srcp = eidx;
  const int* dstp = eidx + N_EDGES;

  hipMemsetAsync(counts, 0, (size_t)N_NODES * 4, stream);
  hipMemsetAsync(ssum, 0, 8 * 128 * 4, stream);
  hipMemsetAsync(ssq, 0, 8 * 128 * 4, stream);
  hipMemsetAsync(pooled, 0, 64 * 128 * 4, stream);
  hipMemsetAsync(gcnt, 0, 64 * 4, stream);

  embed_kernel<<<6250, 256, 0, stream>>>(x_node, emb, hbuf);
  count_kernel<<<(N_EDGES + 255) / 256, 256, 0, stream>>>(dstp, counts);
  scan_block_kernel<<<SCAN_NB, 256, 0, stream>>>(counts, offsets, partials);
  scan_partials_kernel<<<1, 64, 0, stream>>>(partials);
  add_offsets_kernel<<<(N_NODES + 255) / 256, 256, 0, stream>>>(offsets, partials, cursor);
  fill_csr_kernel<<<(N_EDGES + 255) / 256, 256, 0, stream>>>(srcp, dstp, cursor, col);

  for (int l = 0; l < N_LAYERS; ++l) {
    const float* W1 = cw1 + (size_t)l * D * D;
    const float* W2 = cw2 + (size_t)l * D * D;
    float* s1s = ssum + (l * 2) * 128;
    float* s1q = ssq + (l * 2) * 128;
    float* s2s = ssum + (l * 2 + 1) * 128;
    float* s2q = ssq + (l * 2 + 1) * 128;
    float* sc1 = scaleb + (l * 2) * 128;
    float* sh1 = shiftb + (l * 2) * 128;
    float* sc2 = scaleb + (l * 2 + 1) * 128;
    float* sh2 = shiftb + (l * 2 + 1) * 128;
    const float* scp = scaleb + (l * 2 - 1) * 128;  // previous layer's bn2 scale
    const float* shp = shiftb + (l * 2 - 1) * 128;

    if (l == 0)
      agg_kernel<false><<<12500, 256, 0, stream>>>(hbuf, offsets, col, nullptr, nullptr, abuf);
    else
      agg_kernel<true><<<12500, 256, 0, stream>>>(hbuf, offsets, col, scp, shp, abuf);
    gemm_bn_kernel<false><<<782, 256, 0, stream>>>(abuf, W1, cb1 + l * D, nullptr, nullptr,
                                                   ybuf, s1s, s1q);
    finalize_kernel<<<1, 128, 0, stream>>>(s1s, s1q, bn1g + l * D, bn1b + l * D, sc1, sh1);
    gemm_bn_kernel<true><<<782, 256, 0, stream>>>(ybuf, W2, cb2 + l * D, sc1, sh1,
                                                  hbuf, s2s, s2q);
    finalize_kernel<<<1, 128, 0, stream>>>(s2s, s2q, bn2g + l * D, bn2b + l * D, sc2, sh2);
  }

  pool_kernel<<<dim3(64, 8), 256, 0, stream>>>(hbuf, batch,
      scaleb + 7 * 128, shiftb + 7 * 128, pooled, gcnt);
  mlp_kernel<<<64, 256, 0, stream>>>(pooled, gcnt, l1w, l1b, l2w, l2b, out);
}

// Round 3
// 638.377 us; speedup vs baseline: 1.2748x; 1.0867x over previous
//
#include <hip/hip_runtime.h>

#define N_NODES 50000
#define N_EDGES 600000
#define N_GRAPHS 64
#define N_LAYERS 4
#define D 128
#define BN_EPS 1e-5f

#define SCAN_NB 49  // ceil(50000/1024)

typedef __attribute__((ext_vector_type(8))) short short8;
typedef __attribute__((ext_vector_type(4))) float f32x4;

__device__ __forceinline__ unsigned short f32_bf16(float x) {
  unsigned u = __float_as_uint(x);
  u += 0x7FFFu + ((u >> 16) & 1u);  // round-to-nearest-even
  return (unsigned short)(u >> 16);
}
__device__ __forceinline__ float bf16_f32(unsigned short h) {
  return __uint_as_float(((unsigned)h) << 16);
}

// ---------------- embedding gather ----------------
__global__ __launch_bounds__(256) void embed_kernel(const int* __restrict__ idx,
    const float* __restrict__ emb, float* __restrict__ x) {
  int tid = blockIdx.x * 256 + threadIdx.x;
  if (tid >= N_NODES * 32) return;
  int n = tid >> 5, c4 = tid & 31;
  int e = idx[n];
  ((float4*)x)[(size_t)n * 32 + c4] = ((const float4*)emb)[(size_t)e * 32 + c4];
}

// ---------------- CSR build ----------------
__global__ __launch_bounds__(256) void count_kernel(const int* __restrict__ dst,
    int* __restrict__ counts) {
  int e = blockIdx.x * 256 + threadIdx.x;
  if (e < N_EDGES) atomicAdd(&counts[dst[e]], 1);
}

__global__ __launch_bounds__(256) void scan_block_kernel(const int* __restrict__ counts,
    int* __restrict__ offsets, int* __restrict__ partials) {
  __shared__ int s[256];
  int t = threadIdx.x;
  int base = blockIdx.x * 1024 + t * 4;
  int v[4];
#pragma unroll
  for (int i = 0; i < 4; ++i) v[i] = (base + i < N_NODES) ? counts[base + i] : 0;
  int tsum = v[0] + v[1] + v[2] + v[3];
  s[t] = tsum;
  __syncthreads();
  for (int off = 1; off < 256; off <<= 1) {
    int add = (t >= off) ? s[t - off] : 0;
    __syncthreads();
    s[t] += add;
    __syncthreads();
  }
  int run = s[t] - tsum;  // exclusive within block
#pragma unroll
  for (int i = 0; i < 4; ++i) {
    if (base + i < N_NODES) offsets[base + i] = run;
    run += v[i];
  }
  if (t == 255) partials[blockIdx.x] = s[255];
}

__global__ void scan_partials_kernel(int* partials) {
  if (threadIdx.x == 0) {
    int run = 0;
    for (int b = 0; b < SCAN_NB; ++b) { int v = partials[b]; partials[b] = run; run += v; }
  }
}

__global__ __launch_bounds__(256) void add_offsets_kernel(int* __restrict__ offsets,
    const int* __restrict__ partials, int* __restrict__ cursor) {
  int i = blockIdx.x * 256 + threadIdx.x;
  if (i < N_NODES) {
    int o = offsets[i] + partials[i >> 10];
    offsets[i] = o;
    cursor[i] = o;
  }
  if (blockIdx.x == 0 && threadIdx.x == 0) offsets[N_NODES] = N_EDGES;
}

__global__ __launch_bounds__(256) void fill_csr_kernel(const int* __restrict__ src,
    const int* __restrict__ dst, int* __restrict__ cursor, int* __restrict__ col) {
  int e = blockIdx.x * 256 + threadIdx.x;
  if (e < N_EDGES) {
    int d = dst[e];
    int p = atomicAdd(&cursor[d], 1);
    col[p] = src[e];
  }
}

// ---- aggregation: h = t(x[node]) + sum_{src->node} t(x[src]),
//      t = optional fused bn-relu of the PREVIOUS layer ----
template <bool TRANS>
__global__ __launch_bounds__(256) void agg_kernel(const float* __restrict__ x,
    const int* __restrict__ offsets, const int* __restrict__ col,
    const float* __restrict__ scale, const float* __restrict__ shift,
    float* __restrict__ h) {
  int node = blockIdx.x * 4 + (threadIdx.x >> 6);
  int lane = threadIdx.x & 63;
  float2 sc, sh;
  if (TRANS) {
    sc = ((const float2*)scale)[lane];
    sh = ((const float2*)shift)[lane];
  }
  const float2* x2 = (const float2*)x;
  float2 self = x2[(size_t)node * 64 + lane];
  float2 acc;
  if (TRANS) {
    acc.x = fmaxf(fmaf(self.x, sc.x, sh.x), 0.f);
    acc.y = fmaxf(fmaf(self.y, sc.y, sh.y), 0.f);
  } else {
    acc = self;
  }
  int beg = offsets[node], end = offsets[node + 1];
  for (int e = beg; e < end; e += 4) {
    int   idx[4];
    bool  val[4];
#pragma unroll
    for (int i = 0; i < 4; ++i) {
      val[i] = (e + i) < end;
      idx[i] = val[i] ? (e + i) : e;
    }
    int s0 = col[idx[0]], s1 = col[idx[1]], s2 = col[idx[2]], s3 = col[idx[3]];
    float2 v0 = x2[(size_t)s0 * 64 + lane];
    float2 v1 = x2[(size_t)s1 * 64 + lane];
    float2 v2 = x2[(size_t)s2 * 64 + lane];
    float2 v3 = x2[(size_t)s3 * 64 + lane];
    float2 vv[4] = {v0, v1, v2, v3};
#pragma unroll
    for (int i = 0; i < 4; ++i) {
      float2 v = vv[i];
      if (TRANS) {
        v.x = fmaxf(fmaf(v.x, sc.x, sh.x), 0.f);
        v.y = fmaxf(fmaf(v.y, sc.y, sh.y), 0.f);
      }
      if (val[i]) {
        acc.x += v.x;
        acc.y += v.y;
      }
    }
  }
  ((float2*)h)[(size_t)node * 64 + lane] = acc;
}

// ---- W repack: fp32 [k][c] -> MFMA-fragment-ordered bf16 hi/lo planes ----
// frag layout for 16x16x32 B-operand: col = ct*16 + (lane&15), k = ks*32 + (lane>>4)*8 + e
// flat index: ((ks*8 + ct)*64 + lane)*8 + e
__global__ __launch_bounds__(256) void repack_w_kernel(const float* __restrict__ cw1,
    const float* __restrict__ cw2, unsigned short* __restrict__ Wh,
    unsigned short* __restrict__ Wl) {
  int b = blockIdx.x;  // b = l*2 + which
  int l = b >> 1, which = b & 1;
  const float* Wm = (which ? cw2 : cw1) + (size_t)l * D * D;
  unsigned short* outh = Wh + (size_t)b * D * D;
  unsigned short* outl = Wl + (size_t)b * D * D;
  for (int T = threadIdx.x; T < 2048; T += 256) {
    int ks = T >> 9, ct = (T >> 6) & 7, lane = T & 63;
    int kbase = ks * 32 + ((lane >> 4) << 3);
    int c = ct * 16 + (lane & 15);
    unsigned short hs[8], ls[8];
#pragma unroll
    for (int e = 0; e < 8; ++e) {
      float v = Wm[(size_t)(kbase + e) * D + c];
      unsigned short hh = f32_bf16(v);
      hs[e] = hh;
      ls[e] = f32_bf16(v - bf16_f32(hh));
    }
    *(ushort4*)(outh + (size_t)T * 8)     = *(ushort4*)&hs[0];
    *(ushort4*)(outh + (size_t)T * 8 + 4) = *(ushort4*)&hs[4];
    *(ushort4*)(outl + (size_t)T * 8)     = *(ushort4*)&ls[0];
    *(ushort4*)(outl + (size_t)T * 8 + 4) = *(ushort4*)&ls[4];
  }
}

// ---- split-bf16 MFMA GEMM (+optional fused bn-relu on input) + column stats ----
// block: 256 thr = 4 waves, tile 64 rows x 128 cols; wave w: rows w*16..w*16+15, all cols.
template <bool TRANS>
__global__ __launch_bounds__(256) void gemm_mfma_kernel(
    const float* __restrict__ A, const unsigned short* __restrict__ Wh,
    const unsigned short* __restrict__ Wl, const float* __restrict__ bias,
    const float* __restrict__ scale, const float* __restrict__ shift,
    float* __restrict__ Y, float* __restrict__ ssum, float* __restrict__ ssq) {
  __shared__ unsigned short AhL[64][136];  // +8 pad: breaks 256B-stride bank conflicts
  __shared__ unsigned short AlL[64][136];
  int t = threadIdx.x;
  int row0 = blockIdx.x * 64;
  int lane = t & 63;
  int wv = t >> 6;

  // ---- stage A tile: fp32 -> (optional bn-relu) -> bf16 hi/lo in LDS ----
#pragma unroll
  for (int i = 0; i < 8; ++i) {
    int f4 = i * 256 + t;  // 2048 float4 = 64 rows x 32
    int r = f4 >> 5, c4 = f4 & 31;
    int row = row0 + r;
    float4 v = make_float4(0.f, 0.f, 0.f, 0.f);
    if (row < N_NODES) v = ((const float4*)A)[(size_t)row * 32 + c4];
    if (TRANS) {
      float4 sc = ((const float4*)scale)[c4];
      float4 sh = ((const float4*)shift)[c4];
      v.x = fmaxf(fmaf(v.x, sc.x, sh.x), 0.f);
      v.y = fmaxf(fmaf(v.y, sc.y, sh.y), 0.f);
      v.z = fmaxf(fmaf(v.z, sc.z, sh.z), 0.f);
      v.w = fmaxf(fmaf(v.w, sc.w, sh.w), 0.f);
    }
    float xs[4] = {v.x, v.y, v.z, v.w};
    unsigned short hs[4], ls[4];
#pragma unroll
    for (int j = 0; j < 4; ++j) {
      hs[j] = f32_bf16(xs[j]);
      ls[j] = f32_bf16(xs[j] - bf16_f32(hs[j]));
    }
    *(ushort4*)&AhL[r][c4 * 4] = *(ushort4*)hs;
    *(ushort4*)&AlL[r][c4 * 4] = *(ushort4*)ls;
  }
  __syncthreads();

  f32x4 acc[8];
#pragma unroll
  for (int ct = 0; ct < 8; ++ct) acc[ct] = (f32x4){0.f, 0.f, 0.f, 0.f};

  int rw = wv * 16;
  int arow = rw + (lane & 15);
  int kgrp = (lane >> 4) * 8;

#pragma unroll
  for (int ks = 0; ks < 4; ++ks) {
    short8 ahi = *(const short8*)&AhL[arow][ks * 32 + kgrp];
    short8 alo = *(const short8*)&AlL[arow][ks * 32 + kgrp];
    size_t wbase = (size_t)ks * 4096 + (size_t)lane * 8;
#pragma unroll
    for (int ct = 0; ct < 8; ++ct) {
      short8 whi = *(const short8*)(Wh + wbase + (size_t)ct * 512);
      short8 wlo = *(const short8*)(Wl + wbase + (size_t)ct * 512);
      acc[ct] = __builtin_amdgcn_mfma_f32_16x16x32_bf16(ahi, whi, acc[ct], 0, 0, 0);
      acc[ct] = __builtin_amdgcn_mfma_f32_16x16x32_bf16(alo, whi, acc[ct], 0, 0, 0);
      acc[ct] = __builtin_amdgcn_mfma_f32_16x16x32_bf16(ahi, wlo, acc[ct], 0, 0, 0);
    }
  }

  // ---- epilogue: bias, store, per-column stats ----
  int rbase = row0 + rw + ((lane >> 4) << 2);
  int cgrp = lane & 15;
  float csum[8], csq[8];
#pragma unroll
  for (int ct = 0; ct < 8; ++ct) {
    int c = ct * 16 + cgrp;
    float b = bias[c];
    float s = 0.f, q = 0.f;
#pragma unroll
    for (int r = 0; r < 4; ++r) {
      int row = rbase + r;
      if (row < N_NODES) {
        float y = acc[ct][r] + b;
        Y[(size_t)row * D + c] = y;
        s += y;
        q += y * y;
      }
    }
    s += __shfl_xor(s, 16, 64);
    s += __shfl_xor(s, 32, 64);
    q += __shfl_xor(q, 16, 64);
    q += __shfl_xor(q, 32, 64);
    csum[ct] = s;
    csq[ct] = q;
  }
  __syncthreads();  // all waves done with LDS tiles; reuse as reduction scratch
  float* red = (float*)&AhL[0][0];  // needs 1024 floats = 4KB, have 17KB
  if (lane < 16) {
#pragma unroll
    for (int ct = 0; ct < 8; ++ct) {
      red[wv * 128 + ct * 16 + lane] = csum[ct];
      red[512 + wv * 128 + ct * 16 + lane] = csq[ct];
    }
  }
  __syncthreads();
  if (t < 128) {
    float s = red[t] + red[128 + t] + red[256 + t] + red[384 + t];
    atomicAdd(&ssum[t], s);
    float q = red[512 + t] + red[640 + t] + red[768 + t] + red[896 + t];
    atomicAdd(&ssq[t], q);
  }
}

// ---------------- BN finalize: scale/shift per column ----------------
__global__ void finalize_kernel(const float* __restrict__ ssum, const float* __restrict__ ssq,
    const float* __restrict__ g, const float* __restrict__ b,
    float* __restrict__ scale, float* __restrict__ shift) {
  int c = threadIdx.x;
  float mu = ssum[c] * (1.0f / N_NODES);
  float var = fmaxf(ssq[c] * (1.0f / N_NODES) - mu * mu, 0.f);
  float s = g[c] * rsqrtf(var + BN_EPS);
  scale[c] = s;
  shift[c] = fmaf(-mu, s, b[c]);
}

// ---------------- pooling (batch is sorted); applies final bn-relu ----------------
__device__ __forceinline__ int lower_bound_batch(const int* __restrict__ batch, int key) {
  int lo = 0, hi = N_NODES;
  while (lo < hi) {
    int mid = (lo + hi) >> 1;
    if (batch[mid] < key) lo = mid + 1; else hi = mid;
  }
  return lo;
}

__global__ __launch_bounds__(256) void pool_kernel(const float* __restrict__ x,
    const int* __restrict__ batch, const float* __restrict__ scale,
    const float* __restrict__ shift, float* __restrict__ pooled, float* __restrict__ gcnt) {
  int g = blockIdx.x, chunk = blockIdx.y;
  int lo = lower_bound_batch(batch, g);
  int hi = lower_bound_batch(batch, g + 1);
  int f = threadIdx.x & 127, sub = threadIdx.x >> 7;
  float sc = scale[f], sh = shift[f];
  int cnt = hi - lo;
  int per = (cnt + 7) >> 3;
  int s = lo + chunk * per;
  int e = min(s + per, hi);
  float acc = 0.f;
  for (int n = s + sub; n < e; n += 2)
    acc += fmaxf(fmaf(x[(size_t)n * 128 + f], sc, sh), 0.f);
  __shared__ float red[2][128];
  red[sub][f] = acc;
  __syncthreads();
  if (sub == 0) atomicAdd(&pooled[g * 128 + f], red[0][f] + red[1][f]);
  if (threadIdx.x == 0 && chunk == 0) gcnt[g] = (float)cnt;
}

// ---------------- final MLP: relu(pooled/cnt @ W1 + b1) @ W2 + b2 ----------------
__global__ __launch_bounds__(256) void mlp_kernel(const float* __restrict__ pooled,
    const float* __restrict__ gcnt, const float* __restrict__ w1, const float* __restrict__ b1,
    const float* __restrict__ w2, const float* __restrict__ b2, float* __restrict__ out) {
  int g = blockIdx.x, t = threadIdx.x;
  __shared__ float p[128];
  __shared__ float hbuf[256];
  if (t < 128) p[t] = pooled[g * 128 + t] / fmaxf(gcnt[g], 1.0f);
  __syncthreads();
  float acc = b1[t];
  for (int k = 0; k < 128; ++k) acc = fmaf(p[k], w1[k * 256 + t], acc);
  hbuf[t] = fmaxf(acc, 0.f);
  __syncthreads();
  if (t < 10) {
    float o = b2[t];
    for (int k = 0; k < 256; ++k) o = fmaf(hbuf[k], w2[k * 10 + t], o);
    out[g * 10 + t] = o;
  }
}

// ---------------- launch ----------------
extern "C" void kernel_launch(void* const* d_in, const int* in_sizes, int n_in,
                              void* d_out, int out_size, void* d_ws, size_t ws_size,
                              hipStream_t stream) {
  const int* x_node = (const int*)d_in[0];
  const int* eidx = (const int*)d_in[1];
  const int* batch = (const int*)d_in[2];
  const float* emb = (const float*)d_in[3];
  const float* cw1 = (const float*)d_in[4];
  const float* cb1 = (const float*)d_in[5];
  const float* bn1g = (const float*)d_in[6];
  const float* bn1b = (const float*)d_in[7];
  const float* cw2 = (const float*)d_in[8];
  const float* cb2 = (const float*)d_in[9];
  const float* bn2g = (const float*)d_in[10];
  const float* bn2b = (const float*)d_in[11];
  const float* l1w = (const float*)d_in[12];
  const float* l1b = (const float*)d_in[13];
  const float* l2w = (const float*)d_in[14];
  const float* l2b = (const float*)d_in[15];
  float* out = (float*)d_out;

  char* ws = (char*)d_ws;
  size_t off = 0;
  auto carve = [&](size_t bytes) -> void* {
    void* p = ws + off;
    off += (bytes + 255) & ~(size_t)255;
    return p;
  };
  float* hbuf = (float*)carve((size_t)N_NODES * D * 4);  // layer input (raw z, pre-bn)
  float* abuf = (float*)carve((size_t)N_NODES * D * 4);  // agg output
  float* ybuf = (float*)carve((size_t)N_NODES * D * 4);  // gemm1 output (raw z1)
  int* counts = (int*)carve((size_t)N_NODES * 4);
  int* offsets = (int*)carve((size_t)(N_NODES + 1) * 4);
  int* cursor = (int*)carve((size_t)N_NODES * 4);
  int* col = (int*)carve((size_t)N_EDGES * 4);
  int* partials = (int*)carve(64 * 4);
  float* ssum = (float*)carve(8 * 128 * 4);
  float* ssq = (float*)carve(8 * 128 * 4);
  float* scaleb = (float*)carve(8 * 128 * 4);
  float* shiftb = (float*)carve(8 * 128 * 4);
  float* pooled = (float*)carve(64 * 128 * 4);
  float* gcnt = (float*)carve(64 * 4);
  unsigned short* Whb = (unsigned short*)carve((size_t)8 * D * D * 2);
  unsigned short* Wlb = (unsigned short*)carve((size_t)8 * D * D * 2);
  (void)ws_size;
  (void)in_sizes;
  (void)n_in;
  (void)out_size;

  const int* srcp = eidx;
  const int* dstp = eidx + N_EDGES;

  hipMemsetAsync(counts, 0, (size_t)N_NODES * 4, stream);
  hipMemsetAsync(ssum, 0, 8 * 128 * 4, stream);
  hipMemsetAsync(ssq, 0, 8 * 128 * 4, stream);
  hipMemsetAsync(pooled, 0, 64 * 128 * 4, stream);
  hipMemsetAsync(gcnt, 0, 64 * 4, stream);

  repack_w_kernel<<<8, 256, 0, stream>>>(cw1, cw2, Whb, Wlb);
  embed_kernel<<<6250, 256, 0, stream>>>(x_node, emb, hbuf);
  count_kernel<<<(N_EDGES + 255) / 256, 256, 0, stream>>>(dstp, counts);
  scan_block_kernel<<<SCAN_NB, 256, 0, stream>>>(counts, offsets, partials);
  scan_partials_kernel<<<1, 64, 0, stream>>>(partials);
  add_offsets_kernel<<<(N_NODES + 255) / 256, 256, 0, stream>>>(offsets, partials, cursor);
  fill_csr_kernel<<<(N_EDGES + 255) / 256, 256, 0, stream>>>(srcp, dstp, cursor, col);

  for (int l = 0; l < N_LAYERS; ++l) {
    float* s1s = ssum + (l * 2) * 128;
    float* s1q = ssq + (l * 2) * 128;
    float* s2s = ssum + (l * 2 + 1) * 128;
    float* s2q = ssq + (l * 2 + 1) * 128;
    float* sc1 = scaleb + (l * 2) * 128;
    float* sh1 = shiftb + (l * 2) * 128;
    float* sc2 = scaleb + (l * 2 + 1) * 128;
    float* sh2 = shiftb + (l * 2 + 1) * 128;
    const float* scp = scaleb + (l * 2 - 1) * 128;  // previous layer's bn2 scale
    const float* shp = shiftb + (l * 2 - 1) * 128;
    const unsigned short* W1h = Whb + (size_t)(l * 2) * D * D;
    const unsigned short* W1l = Wlb + (size_t)(l * 2) * D * D;
    const unsigned short* W2h = Whb + (size_t)(l * 2 + 1) * D * D;
    const unsigned short* W2l = Wlb + (size_t)(l * 2 + 1) * D * D;

    if (l == 0)
      agg_kernel<false><<<12500, 256, 0, stream>>>(hbuf, offsets, col, nullptr, nullptr, abuf);
    else
      agg_kernel<true><<<12500, 256, 0, stream>>>(hbuf, offsets, col, scp, shp, abuf);
    gemm_mfma_kernel<false><<<782, 256, 0, stream>>>(abuf, W1h, W1l, cb1 + l * D,
                                                     nullptr, nullptr, ybuf, s1s, s1q);
    finalize_kernel<<<1, 128, 0, stream>>>(s1s, s1q, bn1g + l * D, bn1b + l * D, sc1, sh1);
    gemm_mfma_kernel<true><<<782, 256, 0, stream>>>(ybuf, W2h, W2l, cb2 + l * D,
                                                    sc1, sh1, hbuf, s2s, s2q);
    finalize_kernel<<<1, 128, 0, stream>>>(s2s, s2q, bn2g + l * D, bn2b + l * D, sc2, sh2);
  }

  pool_kernel<<<dim3(64, 8), 256, 0, stream>>>(hbuf, batch,
      scaleb + 7 * 128, shiftb + 7 * 128, pooled, gcnt);
  mlp_kernel<<<64, 256, 0, stream>>>(pooled, gcnt, l1w, l1b, l2w, l2b, out);
}

// Round 4
// 526.636 us; speedup vs baseline: 1.5453x; 1.2122x over previous
//
#include <hip/hip_runtime.h>
#include <hip/hip_fp16.h>

#define N_NODES 50000
#define N_EDGES 600000
#define N_GRAPHS 64
#define N_LAYERS 4
#define D 128
#define BN_EPS 1e-5f

#define SCAN_NB 49  // ceil(50000/1024)

typedef __attribute__((ext_vector_type(8))) short short8;
typedef __attribute__((ext_vector_type(4))) float f32x4;

__device__ __forceinline__ unsigned short f32_bf16(float x) {
  unsigned u = __float_as_uint(x);
  u += 0x7FFFu + ((u >> 16) & 1u);  // round-to-nearest-even
  return (unsigned short)(u >> 16);
}
__device__ __forceinline__ float bf16_f32(unsigned short h) {
  return __uint_as_float(((unsigned)h) << 16);
}

// ---------------- embedding gather -> fp16 x ----------------
__global__ __launch_bounds__(256) void embed_kernel(const int* __restrict__ idx,
    const float* __restrict__ emb, __half* __restrict__ xh) {
  int tid = blockIdx.x * 256 + threadIdx.x;
  if (tid >= N_NODES * 32) return;
  int n = tid >> 5, c4 = tid & 31;
  int e = idx[n];
  float4 v = ((const float4*)emb)[(size_t)e * 32 + c4];
  __half2 a = __float22half2_rn(make_float2(v.x, v.y));
  __half2 b = __float22half2_rn(make_float2(v.z, v.w));
  ((__half2*)xh)[(size_t)tid * 2] = a;
  ((__half2*)xh)[(size_t)tid * 2 + 1] = b;
}

// ---------------- CSR build ----------------
__global__ __launch_bounds__(256) void count_kernel(const int* __restrict__ dst,
    int* __restrict__ counts) {
  int e = blockIdx.x * 256 + threadIdx.x;
  if (e < N_EDGES) atomicAdd(&counts[dst[e]], 1);
}

__global__ __launch_bounds__(256) void scan_block_kernel(const int* __restrict__ counts,
    int* __restrict__ offsets, int* __restrict__ partials) {
  __shared__ int s[256];
  int t = threadIdx.x;
  int base = blockIdx.x * 1024 + t * 4;
  int v[4];
#pragma unroll
  for (int i = 0; i < 4; ++i) v[i] = (base + i < N_NODES) ? counts[base + i] : 0;
  int tsum = v[0] + v[1] + v[2] + v[3];
  s[t] = tsum;
  __syncthreads();
  for (int off = 1; off < 256; off <<= 1) {
    int add = (t >= off) ? s[t - off] : 0;
    __syncthreads();
    s[t] += add;
    __syncthreads();
  }
  int run = s[t] - tsum;  // exclusive within block
#pragma unroll
  for (int i = 0; i < 4; ++i) {
    if (base + i < N_NODES) offsets[base + i] = run;
    run += v[i];
  }
  if (t == 255) partials[blockIdx.x] = s[255];
}

__global__ void scan_partials_kernel(int* partials) {
  if (threadIdx.x == 0) {
    int run = 0;
    for (int b = 0; b < SCAN_NB; ++b) { int v = partials[b]; partials[b] = run; run += v; }
  }
}

__global__ __launch_bounds__(256) void add_offsets_kernel(int* __restrict__ offsets,
    const int* __restrict__ partials, int* __restrict__ cursor) {
  int i = blockIdx.x * 256 + threadIdx.x;
  if (i < N_NODES) {
    int o = offsets[i] + partials[i >> 10];
    offsets[i] = o;
    cursor[i] = o;
  }
  if (blockIdx.x == 0 && threadIdx.x == 0) offsets[N_NODES] = N_EDGES;
}

__global__ __launch_bounds__(256) void fill_csr_kernel(const int* __restrict__ src,
    const int* __restrict__ dst, int* __restrict__ cursor, int* __restrict__ col) {
  int e = blockIdx.x * 256 + threadIdx.x;
  if (e < N_EDGES) {
    int d = dst[e];
    int p = atomicAdd(&cursor[d], 1);
    col[p] = src[e];
  }
}

// ---- aggregation: h = x[node] + sum_{src->node} x[src], x in fp16, acc fp32 ----
__global__ __launch_bounds__(256) void agg_kernel(const __half* __restrict__ xh,
    const int* __restrict__ offsets, const int* __restrict__ col,
    float* __restrict__ h) {
  int node = blockIdx.x * 4 + (threadIdx.x >> 6);
  int lane = threadIdx.x & 63;
  const __half2* x2 = (const __half2*)xh;
  float2 acc = __half22float2(x2[(size_t)node * 64 + lane]);
  int beg = offsets[node], end = offsets[node + 1];
  for (int e = beg; e < end; e += 4) {
    int   idx[4];
    bool  val[4];
#pragma unroll
    for (int i = 0; i < 4; ++i) {
      val[i] = (e + i) < end;
      idx[i] = val[i] ? (e + i) : e;
    }
    int s0 = col[idx[0]], s1 = col[idx[1]], s2 = col[idx[2]], s3 = col[idx[3]];
    __half2 v0 = x2[(size_t)s0 * 64 + lane];
    __half2 v1 = x2[(size_t)s1 * 64 + lane];
    __half2 v2 = x2[(size_t)s2 * 64 + lane];
    __half2 v3 = x2[(size_t)s3 * 64 + lane];
    float2 f0 = __half22float2(v0);
    float2 f1 = __half22float2(v1);
    float2 f2 = __half22float2(v2);
    float2 f3 = __half22float2(v3);
    if (val[0]) { acc.x += f0.x; acc.y += f0.y; }
    if (val[1]) { acc.x += f1.x; acc.y += f1.y; }
    if (val[2]) { acc.x += f2.x; acc.y += f2.y; }
    if (val[3]) { acc.x += f3.x; acc.y += f3.y; }
  }
  ((float2*)h)[(size_t)node * 64 + lane] = acc;
}

// ---- W repack: fp32 [k][c] -> MFMA-fragment-ordered bf16 hi/lo planes ----
// frag layout for 16x16x32 B-operand: col = ct*16 + (lane&15), k = ks*32 + (lane>>4)*8 + e
// flat index: ((ks*8 + ct)*64 + lane)*8 + e
__global__ __launch_bounds__(256) void repack_w_kernel(const float* __restrict__ cw1,
    const float* __restrict__ cw2, unsigned short* __restrict__ Wh,
    unsigned short* __restrict__ Wl) {
  int b = blockIdx.x;  // b = l*2 + which
  int l = b >> 1, which = b & 1;
  const float* Wm = (which ? cw2 : cw1) + (size_t)l * D * D;
  unsigned short* outh = Wh + (size_t)b * D * D;
  unsigned short* outl = Wl + (size_t)b * D * D;
  for (int T = threadIdx.x; T < 2048; T += 256) {
    int ks = T >> 9, ct = (T >> 6) & 7, lane = T & 63;
    int kbase = ks * 32 + ((lane >> 4) << 3);
    int c = ct * 16 + (lane & 15);
    unsigned short hs[8], ls[8];
#pragma unroll
    for (int e = 0; e < 8; ++e) {
      float v = Wm[(size_t)(kbase + e) * D + c];
      unsigned short hh = f32_bf16(v);
      hs[e] = hh;
      ls[e] = f32_bf16(v - bf16_f32(hh));
    }
    *(ushort4*)(outh + (size_t)T * 8)     = *(ushort4*)&hs[0];
    *(ushort4*)(outh + (size_t)T * 8 + 4) = *(ushort4*)&hs[4];
    *(ushort4*)(outl + (size_t)T * 8)     = *(ushort4*)&ls[0];
    *(ushort4*)(outl + (size_t)T * 8 + 4) = *(ushort4*)&ls[4];
  }
}

// ---- split-bf16 MFMA GEMM (+optional fused bn-relu on input) + column stats ----
// block: 256 thr = 4 waves, tile 64 rows x 128 cols.
// wave wv computes ALL 64 rows x cols [wv*32, wv*32+32) -> W traffic 64KB/block,
// columns are wave-exclusive -> stats reduce via shfl + direct atomics.
template <bool TRANS>
__global__ __launch_bounds__(256) void gemm_mfma_kernel(
    const float* __restrict__ A, const unsigned short* __restrict__ Wh,
    const unsigned short* __restrict__ Wl, const float* __restrict__ bias,
    const float* __restrict__ scale, const float* __restrict__ shift,
    float* __restrict__ Y, float* __restrict__ ssum, float* __restrict__ ssq) {
  __shared__ unsigned short AhL[64][136];  // +8 pad: breaks 256B-stride bank conflicts
  __shared__ unsigned short AlL[64][136];
  int t = threadIdx.x;
  int row0 = blockIdx.x * 64;
  int lane = t & 63;
  int wv = t >> 6;

  // ---- stage A tile: fp32 -> (optional bn-relu) -> bf16 hi/lo in LDS ----
#pragma unroll
  for (int i = 0; i < 8; ++i) {
    int f4 = i * 256 + t;  // 2048 float4 = 64 rows x 32
    int r = f4 >> 5, c4 = f4 & 31;
    int row = row0 + r;
    float4 v = make_float4(0.f, 0.f, 0.f, 0.f);
    if (row < N_NODES) v = ((const float4*)A)[(size_t)row * 32 + c4];
    if (TRANS) {
      float4 sc = ((const float4*)scale)[c4];
      float4 sh = ((const float4*)shift)[c4];
      v.x = fmaxf(fmaf(v.x, sc.x, sh.x), 0.f);
      v.y = fmaxf(fmaf(v.y, sc.y, sh.y), 0.f);
      v.z = fmaxf(fmaf(v.z, sc.z, sh.z), 0.f);
      v.w = fmaxf(fmaf(v.w, sc.w, sh.w), 0.f);
    }
    float xs[4] = {v.x, v.y, v.z, v.w};
    unsigned short hs[4], ls[4];
#pragma unroll
    for (int j = 0; j < 4; ++j) {
      hs[j] = f32_bf16(xs[j]);
      ls[j] = f32_bf16(xs[j] - bf16_f32(hs[j]));
    }
    *(ushort4*)&AhL[r][c4 * 4] = *(ushort4*)hs;
    *(ushort4*)&AlL[r][c4 * 4] = *(ushort4*)ls;
  }
  __syncthreads();

  f32x4 acc[4][2];  // [row-tile][col-tile]
#pragma unroll
  for (int rt = 0; rt < 4; ++rt)
#pragma unroll
    for (int c = 0; c < 2; ++c) acc[rt][c] = (f32x4){0.f, 0.f, 0.f, 0.f};

  int arow_lo = lane & 15;
  int kgrp = (lane >> 4) * 8;

#pragma unroll
  for (int ks = 0; ks < 4; ++ks) {
    size_t wbase = ((size_t)(ks * 8 + wv * 2) * 64 + lane) * 8;
    short8 wh0 = *(const short8*)(Wh + wbase);
    short8 wl0 = *(const short8*)(Wl + wbase);
    short8 wh1 = *(const short8*)(Wh + wbase + 512);
    short8 wl1 = *(const short8*)(Wl + wbase + 512);
#pragma unroll
    for (int rt = 0; rt < 4; ++rt) {
      short8 ahi = *(const short8*)&AhL[rt * 16 + arow_lo][ks * 32 + kgrp];
      short8 alo = *(const short8*)&AlL[rt * 16 + arow_lo][ks * 32 + kgrp];
      acc[rt][0] = __builtin_amdgcn_mfma_f32_16x16x32_bf16(ahi, wh0, acc[rt][0], 0, 0, 0);
      acc[rt][0] = __builtin_amdgcn_mfma_f32_16x16x32_bf16(alo, wh0, acc[rt][0], 0, 0, 0);
      acc[rt][0] = __builtin_amdgcn_mfma_f32_16x16x32_bf16(ahi, wl0, acc[rt][0], 0, 0, 0);
      acc[rt][1] = __builtin_amdgcn_mfma_f32_16x16x32_bf16(ahi, wh1, acc[rt][1], 0, 0, 0);
      acc[rt][1] = __builtin_amdgcn_mfma_f32_16x16x32_bf16(alo, wh1, acc[rt][1], 0, 0, 0);
      acc[rt][1] = __builtin_amdgcn_mfma_f32_16x16x32_bf16(ahi, wl1, acc[rt][1], 0, 0, 0);
    }
  }

  // ---- epilogue: bias, store, per-column stats (cols wave-exclusive) ----
  int rsub = (lane >> 4) << 2;
#pragma unroll
  for (int cti = 0; cti < 2; ++cti) {
    int c = wv * 32 + cti * 16 + (lane & 15);
    float b = bias[c];
    float s = 0.f, q = 0.f;
#pragma unroll
    for (int rt = 0; rt < 4; ++rt) {
#pragma unroll
      for (int r = 0; r < 4; ++r) {
        int row = row0 + rt * 16 + rsub + r;
        if (row < N_NODES) {
          float y = acc[rt][cti][r] + b;
          Y[(size_t)row * D + c] = y;
          s += y;
          q += y * y;
        }
      }
    }
    s += __shfl_xor(s, 16, 64);
    s += __shfl_xor(s, 32, 64);
    q += __shfl_xor(q, 16, 64);
    q += __shfl_xor(q, 32, 64);
    if (lane < 16) {
      atomicAdd(&ssum[c], s);
      atomicAdd(&ssq[c], q);
    }
  }
}

// ---------------- BN finalize: scale/shift per column ----------------
__global__ void finalize_kernel(const float* __restrict__ ssum, const float* __restrict__ ssq,
    const float* __restrict__ g, const float* __restrict__ b,
    float* __restrict__ scale, float* __restrict__ shift) {
  int c = threadIdx.x;
  float mu = ssum[c] * (1.0f / N_NODES);
  float var = fmaxf(ssq[c] * (1.0f / N_NODES) - mu * mu, 0.f);
  float s = g[c] * rsqrtf(var + BN_EPS);
  scale[c] = s;
  shift[c] = fmaf(-mu, s, b[c]);
}

// ---------------- bn-relu + fp16 convert (feeds next layer's agg) ----------------
__global__ __launch_bounds__(256) void cvt_kernel(const float* __restrict__ z,
    const float* __restrict__ scale, const float* __restrict__ shift,
    __half* __restrict__ xh) {
  int tid = blockIdx.x * 256 + threadIdx.x;
  if (tid >= N_NODES * 32) return;
  int c4 = tid & 31;
  float4 v = ((const float4*)z)[tid];
  float4 sc = ((const float4*)scale)[c4];
  float4 sh = ((const float4*)shift)[c4];
  v.x = fmaxf(fmaf(v.x, sc.x, sh.x), 0.f);
  v.y = fmaxf(fmaf(v.y, sc.y, sh.y), 0.f);
  v.z = fmaxf(fmaf(v.z, sc.z, sh.z), 0.f);
  v.w = fmaxf(fmaf(v.w, sc.w, sh.w), 0.f);
  __half2 a = __float22half2_rn(make_float2(v.x, v.y));
  __half2 b = __float22half2_rn(make_float2(v.z, v.w));
  ((__half2*)xh)[(size_t)tid * 2] = a;
  ((__half2*)xh)[(size_t)tid * 2 + 1] = b;
}

// ---------------- pooling (batch is sorted); applies final bn-relu ----------------
__device__ __forceinline__ int lower_bound_batch(const int* __restrict__ batch, int key) {
  int lo = 0, hi = N_NODES;
  while (lo < hi) {
    int mid = (lo + hi) >> 1;
    if (batch[mid] < key) lo = mid + 1; else hi = mid;
  }
  return lo;
}

__global__ __launch_bounds__(256) void pool_kernel(const float* __restrict__ x,
    const int* __restrict__ batch, const float* __restrict__ scale,
    const float* __restrict__ shift, float* __restrict__ pooled, float* __restrict__ gcnt) {
  int g = blockIdx.x, chunk = blockIdx.y;
  int lo = lower_bound_batch(batch, g);
  int hi = lower_bound_batch(batch, g + 1);
  int f = threadIdx.x & 127, sub = threadIdx.x >> 7;
  float sc = scale[f], sh = shift[f];
  int cnt = hi - lo;
  int per = (cnt + 7) >> 3;
  int s = lo + chunk * per;
  int e = min(s + per, hi);
  float acc = 0.f;
  for (int n = s + sub; n < e; n += 2)
    acc += fmaxf(fmaf(x[(size_t)n * 128 + f], sc, sh), 0.f);
  __shared__ float red[2][128];
  red[sub][f] = acc;
  __syncthreads();
  if (sub == 0) atomicAdd(&pooled[g * 128 + f], red[0][f] + red[1][f]);
  if (threadIdx.x == 0 && chunk == 0) gcnt[g] = (float)cnt;
}

// ---------------- final MLP: relu(pooled/cnt @ W1 + b1) @ W2 + b2 ----------------
__global__ __launch_bounds__(256) void mlp_kernel(const float* __restrict__ pooled,
    const float* __restrict__ gcnt, const float* __restrict__ w1, const float* __restrict__ b1,
    const float* __restrict__ w2, const float* __restrict__ b2, float* __restrict__ out) {
  int g = blockIdx.x, t = threadIdx.x;
  __shared__ float p[128];
  __shared__ float hbuf[256];
  if (t < 128) p[t] = pooled[g * 128 + t] / fmaxf(gcnt[g], 1.0f);
  __syncthreads();
  float acc = b1[t];
  for (int k = 0; k < 128; ++k) acc = fmaf(p[k], w1[k * 256 + t], acc);
  hbuf[t] = fmaxf(acc, 0.f);
  __syncthreads();
  if (t < 10) {
    float o = b2[t];
    for (int k = 0; k < 256; ++k) o = fmaf(hbuf[k], w2[k * 10 + t], o);
    out[g * 10 + t] = o;
  }
}

// ---------------- launch ----------------
extern "C" void kernel_launch(void* const* d_in, const int* in_sizes, int n_in,
                              void* d_out, int out_size, void* d_ws, size_t ws_size,
                              hipStream_t stream) {
  const int* x_node = (const int*)d_in[0];
  const int* eidx = (const int*)d_in[1];
  const int* batch = (const int*)d_in[2];
  const float* emb = (const float*)d_in[3];
  const float* cw1 = (const float*)d_in[4];
  const float* cb1 = (const float*)d_in[5];
  const float* bn1g = (const float*)d_in[6];
  const float* bn1b = (const float*)d_in[7];
  const float* cw2 = (const float*)d_in[8];
  const float* cb2 = (const float*)d_in[9];
  const float* bn2g = (const float*)d_in[10];
  const float* bn2b = (const float*)d_in[11];
  const float* l1w = (const float*)d_in[12];
  const float* l1b = (const float*)d_in[13];
  const float* l2w = (const float*)d_in[14];
  const float* l2b = (const float*)d_in[15];
  float* out = (float*)d_out;

  char* ws = (char*)d_ws;
  size_t off = 0;
  auto carve = [&](size_t bytes) -> void* {
    void* p = ws + off;
    off += (bytes + 255) & ~(size_t)255;
    return p;
  };
  float* hbuf = (float*)carve((size_t)N_NODES * D * 4);  // raw z2 (pre-bn) per layer
  float* abuf = (float*)carve((size_t)N_NODES * D * 4);  // agg output (fp32)
  float* ybuf = (float*)carve((size_t)N_NODES * D * 4);  // gemm1 output (raw z1)
  __half* xh = (__half*)carve((size_t)N_NODES * D * 2);  // fp16 layer input for agg
  int* counts = (int*)carve((size_t)N_NODES * 4);
  int* offsets = (int*)carve((size_t)(N_NODES + 1) * 4);
  int* cursor = (int*)carve((size_t)N_NODES * 4);
  int* col = (int*)carve((size_t)N_EDGES * 4);
  int* partials = (int*)carve(64 * 4);
  float* ssum = (float*)carve(8 * 128 * 4);
  float* ssq = (float*)carve(8 * 128 * 4);
  float* scaleb = (float*)carve(8 * 128 * 4);
  float* shiftb = (float*)carve(8 * 128 * 4);
  float* pooled = (float*)carve(64 * 128 * 4);
  float* gcnt = (float*)carve(64 * 4);
  unsigned short* Whb = (unsigned short*)carve((size_t)8 * D * D * 2);
  unsigned short* Wlb = (unsigned short*)carve((size_t)8 * D * D * 2);
  (void)ws_size;
  (void)in_sizes;
  (void)n_in;
  (void)out_size;

  const int* srcp = eidx;
  const int* dstp = eidx + N_EDGES;

  hipMemsetAsync(counts, 0, (size_t)N_NODES * 4, stream);
  hipMemsetAsync(ssum, 0, 8 * 128 * 4, stream);
  hipMemsetAsync(ssq, 0, 8 * 128 * 4, stream);
  hipMemsetAsync(pooled, 0, 64 * 128 * 4, stream);
  hipMemsetAsync(gcnt, 0, 64 * 4, stream);

  repack_w_kernel<<<8, 256, 0, stream>>>(cw1, cw2, Whb, Wlb);
  embed_kernel<<<6250, 256, 0, stream>>>(x_node, emb, xh);
  count_kernel<<<(N_EDGES + 255) / 256, 256, 0, stream>>>(dstp, counts);
  scan_block_kernel<<<SCAN_NB, 256, 0, stream>>>(counts, offsets, partials);
  scan_partials_kernel<<<1, 64, 0, stream>>>(partials);
  add_offsets_kernel<<<(N_NODES + 255) / 256, 256, 0, stream>>>(offsets, partials, cursor);
  fill_csr_kernel<<<(N_EDGES + 255) / 256, 256, 0, stream>>>(srcp, dstp, cursor, col);

  for (int l = 0; l < N_LAYERS; ++l) {
    float* s1s = ssum + (l * 2) * 128;
    float* s1q = ssq + (l * 2) * 128;
    float* s2s = ssum + (l * 2 + 1) * 128;
    float* s2q = ssq + (l * 2 + 1) * 128;
    float* sc1 = scaleb + (l * 2) * 128;
    float* sh1 = shiftb + (l * 2) * 128;
    float* sc2 = scaleb + (l * 2 + 1) * 128;
    float* sh2 = shiftb + (l * 2 + 1) * 128;
    const unsigned short* W1h = Whb + (size_t)(l * 2) * D * D;
    const unsigned short* W1l = Wlb + (size_t)(l * 2) * D * D;
    const unsigned short* W2h = Whb + (size_t)(l * 2 + 1) * D * D;
    const unsigned short* W2l = Wlb + (size_t)(l * 2 + 1) * D * D;

    agg_kernel<<<12500, 256, 0, stream>>>(xh, offsets, col, abuf);
    gemm_mfma_kernel<false><<<782, 256, 0, stream>>>(abuf, W1h, W1l, cb1 + l * D,
                                                     nullptr, nullptr, ybuf, s1s, s1q);
    finalize_kernel<<<1, 128, 0, stream>>>(s1s, s1q, bn1g + l * D, bn1b + l * D, sc1, sh1);
    gemm_mfma_kernel<true><<<782, 256, 0, stream>>>(ybuf, W2h, W2l, cb2 + l * D,
                                                    sc1, sh1, hbuf, s2s, s2q);
    finalize_kernel<<<1, 128, 0, stream>>>(s2s, s2q, bn2g + l * D, bn2b + l * D, sc2, sh2);
    if (l < N_LAYERS - 1)
      cvt_kernel<<<6250, 256, 0, stream>>>(hbuf, sc2, sh2, xh);
  }

  pool_kernel<<<dim3(64, 8), 256, 0, stream>>>(hbuf, batch,
      scaleb + 7 * 128, shiftb + 7 * 128, pooled, gcnt);
  mlp_kernel<<<64, 256, 0, stream>>>(pooled, gcnt, l1w, l1b, l2w, l2b, out);
}

// Round 6
// 377.769 us; speedup vs baseline: 2.1542x; 1.3941x over previous
//
#include <hip/hip_runtime.h>
#include <hip/hip_fp16.h>

#define N_NODES 50000
#define N_EDGES 600000
#define N_GRAPHS 64
#define N_LAYERS 4
#define D 128
#define BN_EPS 1e-5f

#define SCAN_NB 49   // ceil(50000/1024)
#define GB 782       // gemm grid (ceil(50000/64))

typedef __attribute__((ext_vector_type(8))) short short8;
typedef __attribute__((ext_vector_type(4))) float f32x4;

__device__ __forceinline__ unsigned short f32_bf16(float x) {
  unsigned u = __float_as_uint(x);
  u += 0x7FFFu + ((u >> 16) & 1u);  // round-to-nearest-even
  return (unsigned short)(u >> 16);
}
__device__ __forceinline__ float bf16_f32(unsigned short h) {
  return __uint_as_float(((unsigned)h) << 16);
}
__device__ __forceinline__ float half_bits_to_f32(short b) {
  union { unsigned short u; __half h; } cv;
  cv.u = (unsigned short)b;
  return __half2float(cv.h);
}
__device__ __forceinline__ short f32_to_half_bits(float f) {
  union { __half h; unsigned short u; } cv;
  cv.h = __float2half(f);
  return (short)cv.u;
}

// ---------------- embedding gather -> fp16 x ----------------
__global__ __launch_bounds__(256) void embed_kernel(const int* __restrict__ idx,
    const float* __restrict__ emb, __half* __restrict__ xh) {
  int tid = blockIdx.x * 256 + threadIdx.x;
  if (tid >= N_NODES * 32) return;
  int n = tid >> 5, c4 = tid & 31;
  int e = idx[n];
  float4 v = ((const float4*)emb)[(size_t)e * 32 + c4];
  __half2 a = __float22half2_rn(make_float2(v.x, v.y));
  __half2 b = __float22half2_rn(make_float2(v.z, v.w));
  ((__half2*)xh)[(size_t)tid * 2] = a;
  ((__half2*)xh)[(size_t)tid * 2 + 1] = b;
}

// ---------------- CSR build ----------------
__global__ __launch_bounds__(256) void count_kernel(const int* __restrict__ dst,
    int* __restrict__ counts) {
  int e = blockIdx.x * 256 + threadIdx.x;
  if (e < N_EDGES) atomicAdd(&counts[dst[e]], 1);
}

__global__ __launch_bounds__(256) void scan_block_kernel(const int* __restrict__ counts,
    int* __restrict__ offsets, int* __restrict__ partials) {
  __shared__ int s[256];
  int t = threadIdx.x;
  int base = blockIdx.x * 1024 + t * 4;
  int v[4];
#pragma unroll
  for (int i = 0; i < 4; ++i) v[i] = (base + i < N_NODES) ? counts[base + i] : 0;
  int tsum = v[0] + v[1] + v[2] + v[3];
  s[t] = tsum;
  __syncthreads();
  for (int off = 1; off < 256; off <<= 1) {
    int add = (t >= off) ? s[t - off] : 0;
    __syncthreads();
    s[t] += add;
    __syncthreads();
  }
  int run = s[t] - tsum;  // exclusive within block
#pragma unroll
  for (int i = 0; i < 4; ++i) {
    if (base + i < N_NODES) offsets[base + i] = run;
    run += v[i];
  }
  if (t == 255) partials[blockIdx.x] = s[255];
}

__global__ void scan_partials_kernel(int* partials) {
  if (threadIdx.x == 0) {
    int run = 0;
    for (int b = 0; b < SCAN_NB; ++b) { int v = partials[b]; partials[b] = run; run += v; }
  }
}

__global__ __launch_bounds__(256) void add_offsets_kernel(int* __restrict__ offsets,
    const int* __restrict__ partials, int* __restrict__ cursor) {
  int i = blockIdx.x * 256 + threadIdx.x;
  if (i < N_NODES) {
    int o = offsets[i] + partials[i >> 10];
    offsets[i] = o;
    cursor[i] = o;
  }
  if (blockIdx.x == 0 && threadIdx.x == 0) offsets[N_NODES] = N_EDGES;
}

__global__ __launch_bounds__(256) void fill_csr_kernel(const int* __restrict__ src,
    const int* __restrict__ dst, int* __restrict__ cursor, int* __restrict__ col) {
  int e = blockIdx.x * 256 + threadIdx.x;
  if (e < N_EDGES) {
    int d = dst[e];
    int p = atomicAdd(&cursor[d], 1);
    col[p] = src[e];
  }
}

// ---- aggregation: h = x[node] + sum_{src->node} x[src], x fp16, acc fp32, out fp16 ----
__global__ __launch_bounds__(256) void agg_kernel(const __half* __restrict__ xh,
    const int* __restrict__ offsets, const int* __restrict__ col,
    __half* __restrict__ h) {
  int node = blockIdx.x * 4 + (threadIdx.x >> 6);
  int lane = threadIdx.x & 63;
  const __half2* x2 = (const __half2*)xh;
  float2 acc = __half22float2(x2[(size_t)node * 64 + lane]);
  int beg = offsets[node], end = offsets[node + 1];
  for (int e = beg; e < end; e += 4) {
    int   idx[4];
    bool  val[4];
#pragma unroll
    for (int i = 0; i < 4; ++i) {
      val[i] = (e + i) < end;
      idx[i] = val[i] ? (e + i) : e;
    }
    int s0 = col[idx[0]], s1 = col[idx[1]], s2 = col[idx[2]], s3 = col[idx[3]];
    __half2 v0 = x2[(size_t)s0 * 64 + lane];
    __half2 v1 = x2[(size_t)s1 * 64 + lane];
    __half2 v2 = x2[(size_t)s2 * 64 + lane];
    __half2 v3 = x2[(size_t)s3 * 64 + lane];
    float2 f0 = __half22float2(v0);
    float2 f1 = __half22float2(v1);
    float2 f2 = __half22float2(v2);
    float2 f3 = __half22float2(v3);
    if (val[0]) { acc.x += f0.x; acc.y += f0.y; }
    if (val[1]) { acc.x += f1.x; acc.y += f1.y; }
    if (val[2]) { acc.x += f2.x; acc.y += f2.y; }
    if (val[3]) { acc.x += f3.x; acc.y += f3.y; }
  }
  ((__half2*)h)[(size_t)node * 64 + lane] = __float22half2_rn(acc);
}

// ---- W repack: fp32 [k][c] -> MFMA-fragment-ordered bf16 hi/lo planes ----
// B-frag (16x16x32): col = ct*16 + (lane&15), k = ks*32 + (lane>>4)*8 + e
// flat index: ((ks*8 + ct)*64 + lane)*8 + e
__global__ __launch_bounds__(256) void repack_w_kernel(const float* __restrict__ cw1,
    const float* __restrict__ cw2, unsigned short* __restrict__ Wh,
    unsigned short* __restrict__ Wl) {
  int b = blockIdx.x;  // b = l*2 + which
  int l = b >> 1, which = b & 1;
  const float* Wm = (which ? cw2 : cw1) + (size_t)l * D * D;
  unsigned short* outh = Wh + (size_t)b * D * D;
  unsigned short* outl = Wl + (size_t)b * D * D;
  for (int T = threadIdx.x; T < 2048; T += 256) {
    int ks = T >> 9, ct = (T >> 6) & 7, lane = T & 63;
    int kbase = ks * 32 + ((lane >> 4) << 3);
    int c = ct * 16 + (lane & 15);
    unsigned short hs[8], ls[8];
#pragma unroll
    for (int e = 0; e < 8; ++e) {
      float v = Wm[(size_t)(kbase + e) * D + c];
      unsigned short hh = f32_bf16(v);
      hs[e] = hh;
      ls[e] = f32_bf16(v - bf16_f32(hh));
    }
    *(ushort4*)(outh + (size_t)T * 8)     = *(ushort4*)&hs[0];
    *(ushort4*)(outh + (size_t)T * 8 + 4) = *(ushort4*)&hs[4];
    *(ushort4*)(outl + (size_t)T * 8)     = *(ushort4*)&ls[0];
    *(ushort4*)(outl + (size_t)T * 8 + 4) = *(ushort4*)&ls[4];
  }
}

// ---- split-bf16 MFMA GEMM, fp16 in / fp16 out, per-block column stats (no atomics) ----
// 256 thr = 4 waves; tile 64 rows x 128 cols; wave wv: all rows, cols [wv*32, wv*32+32).
template <bool TRANS>
__global__ __launch_bounds__(256) void gemm_mfma_kernel(
    const __half* __restrict__ A, const unsigned short* __restrict__ Wh,
    const unsigned short* __restrict__ Wl, const float* __restrict__ bias,
    const float* __restrict__ scale, const float* __restrict__ shift,
    __half* __restrict__ Y, float* __restrict__ ps, float* __restrict__ pq) {
  __shared__ unsigned short AhL[64][136];  // +8 pad vs 128: breaks power-of-2 strides
  __shared__ unsigned short AlL[64][136];
  int t = threadIdx.x;
  int row0 = blockIdx.x * 64;
  int lane = t & 63;
  int wv = t >> 6;

  // ---- stage A tile: fp16 -> fp32 -> (optional bn-relu) -> bf16 hi/lo in LDS ----
#pragma unroll
  for (int i = 0; i < 4; ++i) {
    int s = i * 256 + t;        // 1024 chunks of 8 halfs (64 rows x 16)
    int r = s >> 4, c8 = s & 15;
    int row = row0 + r;
    float f[8];
    if (row < N_NODES) {
      short8 v = *(const short8*)(A + (size_t)row * D + c8 * 8);
#pragma unroll
      for (int j = 0; j < 8; ++j) f[j] = half_bits_to_f32(v[j]);
    } else {
#pragma unroll
      for (int j = 0; j < 8; ++j) f[j] = 0.f;
    }
    if (TRANS) {
      float4 sc0 = ((const float4*)scale)[c8 * 2];
      float4 sc1 = ((const float4*)scale)[c8 * 2 + 1];
      float4 sh0 = ((const float4*)shift)[c8 * 2];
      float4 sh1 = ((const float4*)shift)[c8 * 2 + 1];
      float scv[8] = {sc0.x, sc0.y, sc0.z, sc0.w, sc1.x, sc1.y, sc1.z, sc1.w};
      float shv[8] = {sh0.x, sh0.y, sh0.z, sh0.w, sh1.x, sh1.y, sh1.z, sh1.w};
#pragma unroll
      for (int j = 0; j < 8; ++j) f[j] = fmaxf(fmaf(f[j], scv[j], shv[j]), 0.f);
    }
    unsigned short hs[8], ls[8];
#pragma unroll
    for (int j = 0; j < 8; ++j) {
      hs[j] = f32_bf16(f[j]);
      ls[j] = f32_bf16(f[j] - bf16_f32(hs[j]));
    }
    *(ushort4*)&AhL[r][c8 * 8]     = *(ushort4*)&hs[0];
    *(ushort4*)&AhL[r][c8 * 8 + 4] = *(ushort4*)&hs[4];
    *(ushort4*)&AlL[r][c8 * 8]     = *(ushort4*)&ls[0];
    *(ushort4*)&AlL[r][c8 * 8 + 4] = *(ushort4*)&ls[4];
  }
  __syncthreads();

  f32x4 acc[4][2];  // [row-tile][col-tile]
#pragma unroll
  for (int rt = 0; rt < 4; ++rt)
#pragma unroll
    for (int c = 0; c < 2; ++c) acc[rt][c] = (f32x4){0.f, 0.f, 0.f, 0.f};

  int arow_lo = lane & 15;
  int kgrp = (lane >> 4) * 8;

#pragma unroll
  for (int ks = 0; ks < 4; ++ks) {
    size_t wbase = ((size_t)(ks * 8 + wv * 2) * 64 + lane) * 8;
    short8 wh0 = *(const short8*)(Wh + wbase);
    short8 wl0 = *(const short8*)(Wl + wbase);
    short8 wh1 = *(const short8*)(Wh + wbase + 512);
    short8 wl1 = *(const short8*)(Wl + wbase + 512);
#pragma unroll
    for (int rt = 0; rt < 4; ++rt) {
      short8 ahi = *(const short8*)&AhL[rt * 16 + arow_lo][ks * 32 + kgrp];
      short8 alo = *(const short8*)&AlL[rt * 16 + arow_lo][ks * 32 + kgrp];
      acc[rt][0] = __builtin_amdgcn_mfma_f32_16x16x32_bf16(ahi, wh0, acc[rt][0], 0, 0, 0);
      acc[rt][0] = __builtin_amdgcn_mfma_f32_16x16x32_bf16(alo, wh0, acc[rt][0], 0, 0, 0);
      acc[rt][0] = __builtin_amdgcn_mfma_f32_16x16x32_bf16(ahi, wl0, acc[rt][0], 0, 0, 0);
      acc[rt][1] = __builtin_amdgcn_mfma_f32_16x16x32_bf16(ahi, wh1, acc[rt][1], 0, 0, 0);
      acc[rt][1] = __builtin_amdgcn_mfma_f32_16x16x32_bf16(alo, wh1, acc[rt][1], 0, 0, 0);
      acc[rt][1] = __builtin_amdgcn_mfma_f32_16x16x32_bf16(ahi, wl1, acc[rt][1], 0, 0, 0);
    }
  }

  __syncthreads();  // done reading A tiles; reuse AhL as fp16 output staging

  // ---- epilogue: bias, stats (shfl-reduced, plain stores), fp16 via LDS ----
  int rsub = (lane >> 4) << 2;
  int cl = lane & 15;
#pragma unroll
  for (int cti = 0; cti < 2; ++cti) {
    int c = wv * 32 + cti * 16 + cl;
    float b = bias[c];
    float s = 0.f, q = 0.f;
#pragma unroll
    for (int rt = 0; rt < 4; ++rt) {
#pragma unroll
      for (int r = 0; r < 4; ++r) {
        int rl = rt * 16 + rsub + r;
        float y = acc[rt][cti][r] + b;
        ((__half*)&AhL[rl][0])[c] = __float2half(y);
        if (row0 + rl < N_NODES) {
          s += y;
          q += y * y;
        }
      }
    }
    s += __shfl_xor(s, 16, 64);
    s += __shfl_xor(s, 32, 64);
    q += __shfl_xor(q, 16, 64);
    q += __shfl_xor(q, 32, 64);
    if (lane < 16) {
      ps[(size_t)blockIdx.x * 128 + c] = s;
      pq[(size_t)blockIdx.x * 128 + c] = q;
    }
  }
  __syncthreads();
  // coalesced fp16 store: 64 rows x 128 cols
#pragma unroll
  for (int i = 0; i < 4; ++i) {
    int s = i * 256 + t;
    int r = s >> 4, c8 = s & 15;
    int row = row0 + r;
    if (row < N_NODES) {
      ushort4 a = *(ushort4*)&AhL[r][c8 * 8];
      ushort4 b = *(ushort4*)&AhL[r][c8 * 8 + 4];
      *(ushort4*)((unsigned short*)Y + (size_t)row * D + c8 * 8)     = a;
      *(ushort4*)((unsigned short*)Y + (size_t)row * D + c8 * 8 + 4) = b;
    }
  }
}

// ---- BN finalize: reduce per-block partials -> scale/shift per column ----
__global__ __launch_bounds__(256) void finalize_kernel(const float* __restrict__ ps,
    const float* __restrict__ pq, const float* __restrict__ g, const float* __restrict__ b,
    float* __restrict__ scale, float* __restrict__ shift) {
  int c = blockIdx.x;
  int t = threadIdx.x;
  float s = 0.f, q = 0.f;
  for (int i = t; i < GB; i += 256) {
    s += ps[(size_t)i * 128 + c];
    q += pq[(size_t)i * 128 + c];
  }
#pragma unroll
  for (int o = 1; o < 64; o <<= 1) {
    s += __shfl_xor(s, o, 64);
    q += __shfl_xor(q, o, 64);
  }
  __shared__ float rs[4], rq[4];
  if ((t & 63) == 0) { rs[t >> 6] = s; rq[t >> 6] = q; }
  __syncthreads();
  if (t == 0) {
    s = rs[0] + rs[1] + rs[2] + rs[3];
    q = rq[0] + rq[1] + rq[2] + rq[3];
    float mu = s * (1.0f / N_NODES);
    float var = fmaxf(q * (1.0f / N_NODES) - mu * mu, 0.f);
    float sc = g[c] * rsqrtf(var + BN_EPS);
    scale[c] = sc;
    shift[c] = fmaf(-mu, sc, b[c]);
  }
}

// ---------------- bn-relu + fp16 (feeds next layer's agg) ----------------
__global__ __launch_bounds__(256) void cvt_kernel(const __half* __restrict__ z,
    const float* __restrict__ scale, const float* __restrict__ shift,
    __half* __restrict__ xh) {
  int tid = blockIdx.x * 256 + threadIdx.x;
  if (tid >= N_NODES * 16) return;
  int c8 = tid & 15;
  short8 v = ((const short8*)z)[tid];
  float4 sc0 = ((const float4*)scale)[c8 * 2];
  float4 sc1 = ((const float4*)scale)[c8 * 2 + 1];
  float4 sh0 = ((const float4*)shift)[c8 * 2];
  float4 sh1 = ((const float4*)shift)[c8 * 2 + 1];
  float scv[8] = {sc0.x, sc0.y, sc0.z, sc0.w, sc1.x, sc1.y, sc1.z, sc1.w};
  float shv[8] = {sh0.x, sh0.y, sh0.z, sh0.w, sh1.x, sh1.y, sh1.z, sh1.w};
  short8 o;
#pragma unroll
  for (int j = 0; j < 8; ++j) {
    float f = fmaxf(fmaf(half_bits_to_f32(v[j]), scv[j], shv[j]), 0.f);
    o[j] = f32_to_half_bits(f);
  }
  ((short8*)xh)[tid] = o;
}

// ---------------- pooling (batch is sorted); applies final bn-relu ----------------
__device__ __forceinline__ int lower_bound_batch(const int* __restrict__ batch, int key) {
  int lo = 0, hi = N_NODES;
  while (lo < hi) {
    int mid = (lo + hi) >> 1;
    if (batch[mid] < key) lo = mid + 1; else hi = mid;
  }
  return lo;
}

__global__ __launch_bounds__(256) void pool_kernel(const __half* __restrict__ x,
    const int* __restrict__ batch, const float* __restrict__ scale,
    const float* __restrict__ shift, float* __restrict__ pooled, float* __restrict__ gcnt) {
  int g = blockIdx.x, chunk = blockIdx.y;
  int lo = lower_bound_batch(batch, g);
  int hi = lower_bound_batch(batch, g + 1);
  int f = threadIdx.x & 127, sub = threadIdx.x >> 7;
  float sc = scale[f], sh = shift[f];
  int cnt = hi - lo;
  int per = (cnt + 7) >> 3;
  int s = lo + chunk * per;
  int e = min(s + per, hi);
  float acc = 0.f;
  for (int n = s + sub; n < e; n += 2)
    acc += fmaxf(fmaf(__half2float(x[(size_t)n * 128 + f]), sc, sh), 0.f);
  __shared__ float red[2][128];
  red[sub][f] = acc;
  __syncthreads();
  if (sub == 0) atomicAdd(&pooled[g * 128 + f], red[0][f] + red[1][f]);
  if (threadIdx.x == 0 && chunk == 0) gcnt[g] = (float)cnt;
}

// ---------------- final MLP: relu(pooled/cnt @ W1 + b1) @ W2 + b2 ----------------
__global__ __launch_bounds__(256) void mlp_kernel(const float* __restrict__ pooled,
    const float* __restrict__ gcnt, const float* __restrict__ w1, const float* __restrict__ b1,
    const float* __restrict__ w2, const float* __restrict__ b2, float* __restrict__ out) {
  int g = blockIdx.x, t = threadIdx.x;
  __shared__ float p[128];
  __shared__ float hbuf[256];
  if (t < 128) p[t] = pooled[g * 128 + t] / fmaxf(gcnt[g], 1.0f);
  __syncthreads();
  float acc = b1[t];
  for (int k = 0; k < 128; ++k) acc = fmaf(p[k], w1[k * 256 + t], acc);
  hbuf[t] = fmaxf(acc, 0.f);
  __syncthreads();
  if (t < 10) {
    float o = b2[t];
    for (int k = 0; k < 256; ++k) o = fmaf(hbuf[k], w2[k * 10 + t], o);
    out[g * 10 + t] = o;
  }
}

// ---------------- launch ----------------
extern "C" void kernel_launch(void* const* d_in, const int* in_sizes, int n_in,
                              void* d_out, int out_size, void* d_ws, size_t ws_size,
                              hipStream_t stream) {
  const int* x_node = (const int*)d_in[0];
  const int* eidx = (const int*)d_in[1];
  const int* batch = (const int*)d_in[2];
  const float* emb = (const float*)d_in[3];
  const float* cw1 = (const float*)d_in[4];
  const float* cb1 = (const float*)d_in[5];
  const float* bn1g = (const float*)d_in[6];
  const float* bn1b = (const float*)d_in[7];
  const float* cw2 = (const float*)d_in[8];
  const float* cb2 = (const float*)d_in[9];
  const float* bn2g = (const float*)d_in[10];
  const float* bn2b = (const float*)d_in[11];
  const float* l1w = (const float*)d_in[12];
  const float* l1b = (const float*)d_in[13];
  const float* l2w = (const float*)d_in[14];
  const float* l2b = (const float*)d_in[15];
  float* out = (float*)d_out;

  char* ws = (char*)d_ws;
  size_t off = 0;
  auto carve = [&](size_t bytes) -> void* {
    void* p = ws + off;
    off += (bytes + 255) & ~(size_t)255;
    return p;
  };
  __half* xh   = (__half*)carve((size_t)N_NODES * D * 2);  // bn-relu'd layer input
  __half* abuf = (__half*)carve((size_t)N_NODES * D * 2);  // agg output
  __half* ybuf = (__half*)carve((size_t)N_NODES * D * 2);  // gemm1 raw z1
  __half* zbuf = (__half*)carve((size_t)N_NODES * D * 2);  // gemm2 raw z2
  int* counts = (int*)carve((size_t)N_NODES * 4);
  int* offsets = (int*)carve((size_t)(N_NODES + 1) * 4);
  int* cursor = (int*)carve((size_t)N_NODES * 4);
  int* col = (int*)carve((size_t)N_EDGES * 4);
  int* partials = (int*)carve(64 * 4);
  float* part_s = (float*)carve((size_t)GB * 128 * 4);
  float* part_q = (float*)carve((size_t)GB * 128 * 4);
  float* scaleb = (float*)carve(8 * 128 * 4);
  float* shiftb = (float*)carve(8 * 128 * 4);
  float* pooled = (float*)carve(64 * 128 * 4);
  float* gcnt = (float*)carve(64 * 4);
  unsigned short* Whb = (unsigned short*)carve((size_t)8 * D * D * 2);
  unsigned short* Wlb = (unsigned short*)carve((size_t)8 * D * D * 2);
  (void)ws_size;
  (void)in_sizes;
  (void)n_in;
  (void)out_size;

  const int* srcp = eidx;
  const int* dstp = eidx + N_EDGES;

  hipMemsetAsync(counts, 0, (size_t)N_NODES * 4, stream);
  hipMemsetAsync(pooled, 0, 64 * 128 * 4, stream);
  hipMemsetAsync(gcnt, 0, 64 * 4, stream);

  repack_w_kernel<<<8, 256, 0, stream>>>(cw1, cw2, Whb, Wlb);
  embed_kernel<<<6250, 256, 0, stream>>>(x_node, emb, xh);
  count_kernel<<<(N_EDGES + 255) / 256, 256, 0, stream>>>(dstp, counts);
  scan_block_kernel<<<SCAN_NB, 256, 0, stream>>>(counts, offsets, partials);
  scan_partials_kernel<<<1, 64, 0, stream>>>(partials);
  add_offsets_kernel<<<(N_NODES + 255) / 256, 256, 0, stream>>>(offsets, partials, cursor);
  fill_csr_kernel<<<(N_EDGES + 255) / 256, 256, 0, stream>>>(srcp, dstp, cursor, col);

  for (int l = 0; l < N_LAYERS; ++l) {
    float* sc1 = scaleb + (l * 2) * 128;
    float* sh1 = shiftb + (l * 2) * 128;
    float* sc2 = scaleb + (l * 2 + 1) * 128;
    float* sh2 = shiftb + (l * 2 + 1) * 128;
    const unsigned short* W1h = Whb + (size_t)(l * 2) * D * D;
    const unsigned short* W1l = Wlb + (size_t)(l * 2) * D * D;
    const unsigned short* W2h = Whb + (size_t)(l * 2 + 1) * D * D;
    const unsigned short* W2l = Wlb + (size_t)(l * 2 + 1) * D * D;

    agg_kernel<<<12500, 256, 0, stream>>>(xh, offsets, col, abuf);
    gemm_mfma_kernel<false><<<GB, 256, 0, stream>>>(abuf, W1h, W1l, cb1 + l * D,
                                                    nullptr, nullptr, ybuf, part_s, part_q);
    finalize_kernel<<<128, 256, 0, stream>>>(part_s, part_q, bn1g + l * D, bn1b + l * D,
                                             sc1, sh1);
    gemm_mfma_kernel<true><<<GB, 256, 0, stream>>>(ybuf, W2h, W2l, cb2 + l * D,
                                                   sc1, sh1, zbuf, part_s, part_q);
    finalize_kernel<<<128, 256, 0, stream>>>(part_s, part_q, bn2g + l * D, bn2b + l * D,
                                             sc2, sh2);
    if (l < N_LAYERS - 1)
      cvt_kernel<<<3125, 256, 0, stream>>>(zbuf, sc2, sh2, xh);
  }

  pool_kernel<<<dim3(64, 8), 256, 0, stream>>>(zbuf, batch,
      scaleb + 7 * 128, shiftb + 7 * 128, pooled, gcnt);
  mlp_kernel<<<64, 256, 0, stream>>>(pooled, gcnt, l1w, l1b, l2w, l2b, out);
}